// Round 1
// baseline (4393.291 us; speedup 1.0000x reference)
//
#include <hip/hip_runtime.h>
#include <math.h>

typedef unsigned short ushort_t;
typedef unsigned long long u64;
typedef unsigned int uint32;

#define B_ 8
#define N_ 4096
#define S_ 1024
#define K_ 32
#define C_ 128
#define NCOL1 (B_*S_*K_)   // 262144
#define NCOL2 (B_*S_)      // 8192
#define EPS_ 1e-5f

typedef ushort_t us8 __attribute__((ext_vector_type(8)));

__device__ __forceinline__ float bf2f(ushort_t u){ return __uint_as_float(((uint32)u)<<16); }
__device__ __forceinline__ ushort_t f2bf(float f){
    uint32 x = __float_as_uint(f);
    return (ushort_t)((x + 0x7FFFu + ((x>>16)&1u)) >> 16);
}
__device__ __forceinline__ float gelu_f(float v){
    return 0.5f*v*(1.0f + erff(v*0.70710678118654752f));
}
__device__ __forceinline__ u64 shfl_xor_u64(u64 v, int m){
    int lo = __shfl_xor((int)(v & 0xFFFFFFFFull), m, 64);
    int hi = __shfl_xor((int)(v >> 32), m, 64);
    return (((u64)(uint32)hi) << 32) | (uint32)lo;
}

// ---------------- transpose x (B,64,N) -> xT (B,N,64) ----------------
__global__ __launch_bounds__(256) void transpose_kernel(const float* __restrict__ x, float* __restrict__ xT){
    __shared__ float t[64][65];
    int b  = blockIdx.x >> 6;
    int n0 = (blockIdx.x & 63) * 64;
    int tx = threadIdx.x & 63, ty = threadIdx.x >> 6;
    #pragma unroll
    for (int i=0;i<16;i++){
        int c = i*4 + ty;
        t[c][tx] = x[((long)(b*64 + c))*N_ + n0 + tx];
    }
    __syncthreads();
    #pragma unroll
    for (int i=0;i<16;i++){
        int n = i*4 + ty;
        xT[((long)(b*N_ + n0 + n))*64 + tx] = t[tx][n];
    }
}

// ---------------- KNN: per query block, exact top-32 smallest distances ----------------
__global__ __launch_bounds__(256) void knn_kernel(const float* __restrict__ xyz, const int* __restrict__ fps,
                                                  int* __restrict__ idxg, float* __restrict__ newxyz){
    int bs = blockIdx.x;            // b*S + s
    int b  = bs >> 10;
    int qi = fps[bs];
    const float* qb = xyz + ((long)b*N_ + qi)*3;
    float qx = qb[0], qy = qb[1], qz = qb[2];
    if (threadIdx.x < 3) newxyz[(long)bs*3 + threadIdx.x] = qb[threadIdx.x];

    const float* xb = xyz + (long)b*N_*3;
    u64 key[16];
    #pragma unroll
    for (int i=0;i<16;i++){
        int n = i*256 + threadIdx.x;
        float dx = xb[n*3+0]-qx, dy = xb[n*3+1]-qy, dz = xb[n*3+2]-qz;
        float d = dx*dx + dy*dy + dz*dz;          // >= 0 always
        key[i] = (((u64)__float_as_uint(d)) << 32) | (uint32)n;  // tie-break: lower index
    }
    __shared__ u64 wred[4];
    __shared__ u64 winner;
    uint32 alive = 0xFFFFu;
    for (int r=0;r<K_;r++){
        u64 lmin = ~0ull;
        #pragma unroll
        for (int i=0;i<16;i++){
            u64 k = key[i];
            if (((alive>>i)&1u) && k < lmin) lmin = k;
        }
        #pragma unroll
        for (int off=32; off>=1; off>>=1){
            u64 o = shfl_xor_u64(lmin, off);
            if (o < lmin) lmin = o;
        }
        if ((threadIdx.x & 63) == 0) wred[threadIdx.x>>6] = lmin;
        __syncthreads();
        if (threadIdx.x == 0){
            u64 m = wred[0];
            if (wred[1]<m) m=wred[1];
            if (wred[2]<m) m=wred[2];
            if (wred[3]<m) m=wred[3];
            winner = m;
            idxg[(long)bs*K_ + r] = (int)(m & 0xFFFFFFFFull);
        }
        __syncthreads();
        u64 w = winner;
        #pragma unroll
        for (int i=0;i<16;i++) if (key[i] == w) alive &= ~(1u<<i);
    }
}

// ---------------- build features: A[col][c], col=(b*S+s)*K+k ----------------
__global__ __launch_bounds__(256) void build_kernel(const float* __restrict__ xT, const int* __restrict__ fps,
                                                    const int* __restrict__ idxg, ushort_t* __restrict__ A){
    long col = (long)blockIdx.x*256 + threadIdx.x;
    long bs  = col >> 5;
    int  b   = (int)(bs >> 10);
    int  n   = idxg[col];
    int  cn  = fps[bs];
    const float4* pr = (const float4*)(xT + ((long)b*N_ + n )*64);
    const float4* cr = (const float4*)(xT + ((long)b*N_ + cn)*64);
    ushort_t* op = A + col*C_;
    #pragma unroll
    for (int j=0;j<16;j++){
        float4 p = pr[j], c = cr[j];
        uint2 d, e;
        d.x = (((uint32)f2bf(p.y-c.y))<<16) | f2bf(p.x-c.x);
        d.y = (((uint32)f2bf(p.w-c.w))<<16) | f2bf(p.z-c.z);
        e.x = (((uint32)f2bf(c.y))<<16) | f2bf(c.x);
        e.y = (((uint32)f2bf(c.w))<<16) | f2bf(c.z);
        *(uint2*)(op + j*4)      = d;
        *(uint2*)(op + 64 + j*4) = e;
    }
}

// ---------------- conv: out[col][oc] = sum_c W[oc][c]*pre(in[col][c]) ----------------
// thread: one column (lane) x 32 output channels (wave group). W read via wave-uniform s_loads.
template<int PRE>
__global__ __launch_bounds__(256) void conv_kernel(const ushort_t* __restrict__ in, ushort_t* __restrict__ out,
                                                   const float* __restrict__ W, const float* __restrict__ scsh){
    int lane = threadIdx.x & 63;
    int ogrp = __builtin_amdgcn_readfirstlane((int)(threadIdx.x >> 6));
    long col = (long)blockIdx.x*64 + lane;
    const us8* ip = (const us8*)(in + col*C_);
    const float2* ss2 = (const float2*)scsh;
    float xv[C_];
    #pragma unroll
    for (int j=0;j<16;j++){
        us8 v = ip[j];
        #pragma unroll
        for (int e=0;e<8;e++){
            int c = j*8+e;
            float f = bf2f(v[e]);
            if (PRE){
                float2 ss = ss2[c];
                f = gelu_f(fmaf(f, ss.x, ss.y));
            }
            xv[c] = f;
        }
    }
    __syncthreads();   // in-place safety: all column loads complete before any store
    #pragma unroll 1
    for (int oq=0; oq<8; oq++){
        int oc0 = (ogrp<<5) | (oq<<2);
        const float4* w0 = (const float4*)(W + (oc0  )*C_);
        const float4* w1 = (const float4*)(W + (oc0+1)*C_);
        const float4* w2 = (const float4*)(W + (oc0+2)*C_);
        const float4* w3 = (const float4*)(W + (oc0+3)*C_);
        float a0=0.f,a1=0.f,a2=0.f,a3=0.f;
        #pragma unroll
        for (int cq=0; cq<32; cq++){
            float4 wa = w0[cq], wb = w1[cq], wc = w2[cq], wd = w3[cq];
            float x0 = xv[cq*4+0], x1 = xv[cq*4+1], x2 = xv[cq*4+2], x3 = xv[cq*4+3];
            a0 = fmaf(wa.x,x0,a0); a0 = fmaf(wa.y,x1,a0); a0 = fmaf(wa.z,x2,a0); a0 = fmaf(wa.w,x3,a0);
            a1 = fmaf(wb.x,x0,a1); a1 = fmaf(wb.y,x1,a1); a1 = fmaf(wb.z,x2,a1); a1 = fmaf(wb.w,x3,a1);
            a2 = fmaf(wc.x,x0,a2); a2 = fmaf(wc.y,x1,a2); a2 = fmaf(wc.z,x2,a2); a2 = fmaf(wc.w,x3,a2);
            a3 = fmaf(wd.x,x0,a3); a3 = fmaf(wd.y,x1,a3); a3 = fmaf(wd.z,x2,a3); a3 = fmaf(wd.w,x3,a3);
        }
        uint2 st;
        st.x = (((uint32)f2bf(a1))<<16) | f2bf(a0);
        st.y = (((uint32)f2bf(a3))<<16) | f2bf(a2);
        *(uint2*)(out + col*C_ + oc0) = st;
    }
}

// ---------------- per-channel sum/sumsq over all columns ----------------
__global__ __launch_bounds__(256) void stats_kernel(const ushort_t* __restrict__ T, float* __restrict__ st, int ncol){
    int cp  = threadIdx.x & 63;   // channel pair: c0 = cp*2
    int row = threadIdx.x >> 6;   // 0..3
    float s0=0.f,q0=0.f,s1=0.f,q1=0.f;
    for (long col = (long)blockIdx.x*4 + row; col < ncol; col += (long)gridDim.x*4){
        uint32 v = *(const uint32*)(T + col*C_ + cp*2);
        float f0 = bf2f((ushort_t)(v & 0xFFFFu));
        float f1 = bf2f((ushort_t)(v >> 16));
        s0 += f0; q0 += f0*f0; s1 += f1; q1 += f1*f1;
    }
    __shared__ float rs0[256], rq0[256], rs1[256], rq1[256];
    rs0[threadIdx.x]=s0; rq0[threadIdx.x]=q0; rs1[threadIdx.x]=s1; rq1[threadIdx.x]=q1;
    __syncthreads();
    if (threadIdx.x < 64){
        int c0 = threadIdx.x*2;
        float ts0=0.f,tq0=0.f,ts1=0.f,tq1=0.f;
        #pragma unroll
        for (int r=0;r<4;r++){
            ts0 += rs0[r*64+threadIdx.x]; tq0 += rq0[r*64+threadIdx.x];
            ts1 += rs1[r*64+threadIdx.x]; tq1 += rq1[r*64+threadIdx.x];
        }
        atomicAdd(&st[c0*2+0], ts0); atomicAdd(&st[c0*2+1], tq0);
        atomicAdd(&st[(c0+1)*2+0], ts1); atomicAdd(&st[(c0+1)*2+1], tq1);
    }
}

// ---------------- (sum,sumsq) -> (scale, shift) ----------------
__global__ void finalize_kernel(const float* __restrict__ st, float* __restrict__ scsh,
                                const float* __restrict__ g, const float* __restrict__ bb, float inv_cnt){
    int c = threadIdx.x;
    float mean = st[c*2]*inv_cnt;
    float var  = st[c*2+1]*inv_cnt - mean*mean;
    float rs   = rsqrtf(var + EPS_);
    float sc   = g[c]*rs;
    scsh[c*2+0] = sc;
    scsh[c*2+1] = bb[c] - mean*sc;
}

// ---------------- A = gelu(bn(T) + A) ----------------
__global__ __launch_bounds__(256) void resid_kernel(ushort_t* __restrict__ A, const ushort_t* __restrict__ T,
                                                    const float* __restrict__ scsh){
    __shared__ float ss[256];
    ss[threadIdx.x] = scsh[threadIdx.x];
    __syncthreads();
    long t = (long)blockIdx.x*256 + threadIdx.x;
    long base = t*8;
    int c0 = (int)(base & (C_-1));
    us8 av = *(const us8*)(A+base);
    us8 tv = *(const us8*)(T+base);
    us8 r;
    #pragma unroll
    for (int j=0;j<8;j++){
        float sc = ss[(c0+j)*2], sh = ss[(c0+j)*2+1];
        float f = gelu_f(fmaf(bf2f(tv[j]), sc, sh) + bf2f(av[j]));
        r[j] = f2bf(f);
    }
    *(us8*)(A+base) = r;
}

// ---------------- max over K: A1 (bs,k,c) -> A2 (bs,c) ----------------
__global__ __launch_bounds__(256) void pool_kernel(const ushort_t* __restrict__ A1, ushort_t* __restrict__ A2){
    long p  = (long)blockIdx.x*256 + threadIdx.x;    // 8192*64
    long bs = p >> 6;
    int  c0 = ((int)p & 63)*2;
    const ushort_t* base = A1 + (bs*K_)*(long)C_ + c0;
    float m0 = -1e30f, m1 = -1e30f;
    #pragma unroll
    for (int k=0;k<K_;k++){
        uint32 v = *(const uint32*)(base + (long)k*C_);
        m0 = fmaxf(m0, bf2f((ushort_t)(v & 0xFFFFu)));
        m1 = fmaxf(m1, bf2f((ushort_t)(v >> 16)));
    }
    uint32 o = (((uint32)f2bf(m1))<<16) | f2bf(m0);
    *(uint32*)(A2 + bs*C_ + c0) = o;
}

// ---------------- final output: y[b][c][s] = A2[b*S+s][c] ----------------
__global__ __launch_bounds__(256) void out_kernel(const ushort_t* __restrict__ A2, float* __restrict__ y){
    long o = (long)blockIdx.x*256 + threadIdx.x;     // B*C*S
    int s = (int)(o & (S_-1));
    int c = (int)((o >> 10) & (C_-1));
    int b = (int)(o >> 17);
    y[o] = bf2f(A2[((long)(b*S_ + s))*C_ + c]);
}

// ---------------- host side ----------------
static void run_ext(ushort_t* A, ushort_t* Bb, long ncol,
                    const float* convw, const float* g, const float* b,
                    const float* fw, const float* fg, const float* fb,
                    float* st, float* scsh, float inv_cnt, hipStream_t stream){
    int cgrid = (int)(ncol/64);
    int rgrid = (int)((ncol*(long)C_)/(256*8));
    const float* W[5]  = {convw, convw+C_*C_, convw+2*C_*C_, convw+3*C_*C_, fw};
    const float* G[5]  = {g, g+C_, g+2*C_, g+3*C_, fg};
    const float* Bv[5] = {b, b+C_, b+2*C_, b+3*C_, fb};

    // res block 0
    conv_kernel<0><<<cgrid,256,0,stream>>>(A, Bb, W[0], nullptr);
    stats_kernel<<<512,256,0,stream>>>(Bb, st+0*256, (int)ncol);
    finalize_kernel<<<1,128,0,stream>>>(st+0*256, scsh+0*256, G[0], Bv[0], inv_cnt);
    conv_kernel<1><<<cgrid,256,0,stream>>>(Bb, Bb, W[1], scsh+0*256);
    stats_kernel<<<512,256,0,stream>>>(Bb, st+1*256, (int)ncol);
    finalize_kernel<<<1,128,0,stream>>>(st+1*256, scsh+1*256, G[1], Bv[1], inv_cnt);
    resid_kernel<<<rgrid,256,0,stream>>>(A, Bb, scsh+1*256);
    // res block 1
    conv_kernel<0><<<cgrid,256,0,stream>>>(A, Bb, W[2], nullptr);
    stats_kernel<<<512,256,0,stream>>>(Bb, st+2*256, (int)ncol);
    finalize_kernel<<<1,128,0,stream>>>(st+2*256, scsh+2*256, G[2], Bv[2], inv_cnt);
    conv_kernel<1><<<cgrid,256,0,stream>>>(Bb, Bb, W[3], scsh+2*256);
    stats_kernel<<<512,256,0,stream>>>(Bb, st+3*256, (int)ncol);
    finalize_kernel<<<1,128,0,stream>>>(st+3*256, scsh+3*256, G[3], Bv[3], inv_cnt);
    resid_kernel<<<rgrid,256,0,stream>>>(A, Bb, scsh+3*256);
    // final ffn
    conv_kernel<0><<<cgrid,256,0,stream>>>(A, Bb, W[4], nullptr);
    stats_kernel<<<512,256,0,stream>>>(Bb, st+4*256, (int)ncol);
    finalize_kernel<<<1,128,0,stream>>>(st+4*256, scsh+4*256, G[4], Bv[4], inv_cnt);
    resid_kernel<<<rgrid,256,0,stream>>>(A, Bb, scsh+4*256);
}

extern "C" void kernel_launch(void* const* d_in, const int* in_sizes, int n_in,
                              void* d_out, int out_size, void* d_ws, size_t ws_size,
                              hipStream_t stream){
    const float* xyz        = (const float*)d_in[0];
    const float* x          = (const float*)d_in[1];
    const int*   fps        = (const int*)d_in[2];
    const float* pre_conv_w = (const float*)d_in[3];
    const float* pre_bn_g   = (const float*)d_in[4];
    const float* pre_bn_b   = (const float*)d_in[5];
    const float* pre_ffn_w  = (const float*)d_in[6];
    const float* pre_ffn_g  = (const float*)d_in[7];
    const float* pre_ffn_b  = (const float*)d_in[8];
    const float* pos_conv_w = (const float*)d_in[9];
    const float* pos_bn_g   = (const float*)d_in[10];
    const float* pos_bn_b   = (const float*)d_in[11];
    const float* pos_ffn_w  = (const float*)d_in[12];
    const float* pos_ffn_g  = (const float*)d_in[13];
    const float* pos_ffn_b  = (const float*)d_in[14];

    float* out_xyz = (float*)d_out;
    float* out_y   = (float*)d_out + (long)B_*S_*3;

    // workspace layout (bytes): stats 10240 | scsh 10240 | idx 1 MiB | xT 8 MiB | A1 64 MiB | B1 64 MiB | A2 2 MiB | B2 2 MiB
    char* ws = (char*)d_ws;
    float*    st    = (float*)(ws + 0);
    float*    scsh  = (float*)(ws + 10240);
    int*      idx   = (int*)(ws + 20480);
    float*    xT    = (float*)(ws + 1069056);
    ushort_t* A1    = (ushort_t*)(ws + 9457664);
    ushort_t* B1    = (ushort_t*)(ws + 76566528);
    ushort_t* A2    = (ushort_t*)(ws + 143675392);
    ushort_t* B2    = (ushort_t*)(ws + 145772544);
    (void)in_sizes; (void)n_in; (void)out_size; (void)ws_size;

    hipMemsetAsync(st, 0, 10240, stream);                                  // zero BN accumulators
    transpose_kernel<<<B_*(N_/64),256,0,stream>>>(x, xT);
    knn_kernel<<<B_*S_,256,0,stream>>>(xyz, fps, idx, out_xyz);
    build_kernel<<<NCOL1/256,256,0,stream>>>(xT, fps, idx, A1);

    run_ext(A1, B1, NCOL1, pre_conv_w, pre_bn_g, pre_bn_b,
            pre_ffn_w, pre_ffn_g, pre_ffn_b, st, scsh, 1.0f/(float)NCOL1, stream);

    pool_kernel<<<(NCOL2*64)/256,256,0,stream>>>(A1, A2);

    run_ext(A2, B2, NCOL2, pos_conv_w, pos_bn_g, pos_bn_b,
            pos_ffn_w, pos_ffn_g, pos_ffn_b, st+5*256, scsh+5*256, 1.0f/(float)NCOL2, stream);

    out_kernel<<<(B_*C_*S_)/256,256,0,stream>>>(A2, out_y);
}

// Round 2
// 999.755 us; speedup vs baseline: 4.3944x; 4.3944x over previous
//
#include <hip/hip_runtime.h>
#include <math.h>

typedef unsigned short ushort_t;
typedef unsigned long long u64;
typedef unsigned int uint32;

#define B_ 8
#define N_ 4096
#define S_ 1024
#define K_ 32
#define C_ 128
#define NCOL1 (B_*S_*K_)   // 262144
#define NCOL2 (B_*S_)      // 8192
#define EPS_ 1e-5f

typedef ushort_t us8 __attribute__((ext_vector_type(8)));
typedef short s16x8 __attribute__((ext_vector_type(8)));
typedef float f32x4 __attribute__((ext_vector_type(4)));

__device__ __forceinline__ float bf2f(ushort_t u){ return __uint_as_float(((uint32)u)<<16); }
__device__ __forceinline__ ushort_t f2bf(float f){
    uint32 x = __float_as_uint(f);
    return (ushort_t)((x + 0x7FFFu + ((x>>16)&1u)) >> 16);
}
__device__ __forceinline__ float gelu_f(float v){
    return 0.5f*v*(1.0f + erff(v*0.70710678118654752f));
}
__device__ __forceinline__ u64 shfl_xor_u64(u64 v, int m){
    int lo = __shfl_xor((int)(v & 0xFFFFFFFFull), m, 64);
    int hi = __shfl_xor((int)(v >> 32), m, 64);
    return (((u64)(uint32)hi) << 32) | (uint32)lo;
}

// ---------------- transpose x (B,64,N) -> xT (B,N,64) ----------------
__global__ __launch_bounds__(256) void transpose_kernel(const float* __restrict__ x, float* __restrict__ xT){
    __shared__ float t[64][65];
    int b  = blockIdx.x >> 6;
    int n0 = (blockIdx.x & 63) * 64;
    int tx = threadIdx.x & 63, ty = threadIdx.x >> 6;
    #pragma unroll
    for (int i=0;i<16;i++){
        int c = i*4 + ty;
        t[c][tx] = x[((long)(b*64 + c))*N_ + n0 + tx];
    }
    __syncthreads();
    #pragma unroll
    for (int i=0;i<16;i++){
        int n = i*4 + ty;
        xT[((long)(b*N_ + n0 + n))*64 + tx] = t[tx][n];
    }
}

// ---------------- KNN: exact top-32 smallest distances per query ----------------
__global__ __launch_bounds__(256) void knn_kernel(const float* __restrict__ xyz, const int* __restrict__ fps,
                                                  int* __restrict__ idxg, float* __restrict__ newxyz){
    int bs = blockIdx.x;            // b*S + s
    int b  = bs >> 10;
    int qi = fps[bs];
    const float* qb = xyz + ((long)b*N_ + qi)*3;
    float qx = qb[0], qy = qb[1], qz = qb[2];
    if (threadIdx.x < 3) newxyz[(long)bs*3 + threadIdx.x] = qb[threadIdx.x];

    const float* xb = xyz + (long)b*N_*3;
    u64 key[16];
    #pragma unroll
    for (int i=0;i<16;i++){
        int n = i*256 + threadIdx.x;
        float dx = xb[n*3+0]-qx, dy = xb[n*3+1]-qy, dz = xb[n*3+2]-qz;
        float d = dx*dx + dy*dy + dz*dz;          // >= 0 always
        key[i] = (((u64)__float_as_uint(d)) << 32) | (uint32)n;  // tie-break: lower index
    }
    __shared__ u64 wred[4];
    __shared__ u64 winner;
    uint32 alive = 0xFFFFu;
    for (int r=0;r<K_;r++){
        u64 lmin = ~0ull;
        #pragma unroll
        for (int i=0;i<16;i++){
            u64 k = key[i];
            if (((alive>>i)&1u) && k < lmin) lmin = k;
        }
        #pragma unroll
        for (int off=32; off>=1; off>>=1){
            u64 o = shfl_xor_u64(lmin, off);
            if (o < lmin) lmin = o;
        }
        if ((threadIdx.x & 63) == 0) wred[threadIdx.x>>6] = lmin;
        __syncthreads();
        if (threadIdx.x == 0){
            u64 m = wred[0];
            if (wred[1]<m) m=wred[1];
            if (wred[2]<m) m=wred[2];
            if (wred[3]<m) m=wred[3];
            winner = m;
            idxg[(long)bs*K_ + r] = (int)(m & 0xFFFFFFFFull);
        }
        __syncthreads();
        u64 w = winner;
        #pragma unroll
        for (int i=0;i<16;i++) if (key[i] == w) alive &= ~(1u<<i);
    }
}

// ---------------- build features: A[col][c], col=(b*S+s)*K+k ----------------
__global__ __launch_bounds__(256) void build_kernel(const float* __restrict__ xT, const int* __restrict__ fps,
                                                    const int* __restrict__ idxg, ushort_t* __restrict__ A){
    long col = (long)blockIdx.x*256 + threadIdx.x;
    long bs  = col >> 5;
    int  b   = (int)(bs >> 10);
    int  n   = idxg[col];
    int  cn  = fps[bs];
    const float4* pr = (const float4*)(xT + ((long)b*N_ + n )*64);
    const float4* cr = (const float4*)(xT + ((long)b*N_ + cn)*64);
    ushort_t* op = A + col*C_;
    #pragma unroll
    for (int j=0;j<16;j++){
        float4 p = pr[j], c = cr[j];
        uint2 d, e;
        d.x = (((uint32)f2bf(p.y-c.y))<<16) | f2bf(p.x-c.x);
        d.y = (((uint32)f2bf(p.w-c.w))<<16) | f2bf(p.z-c.z);
        e.x = (((uint32)f2bf(c.y))<<16) | f2bf(c.x);
        e.y = (((uint32)f2bf(c.w))<<16) | f2bf(c.z);
        *(uint2*)(op + j*4)      = d;
        *(uint2*)(op + 64 + j*4) = e;
    }
}

// ---------------- convert all 10 weight matrices f32 -> bf16 ----------------
__global__ __launch_bounds__(256) void wcvt_kernel(const float* __restrict__ pcw, const float* __restrict__ pfw,
                                                   const float* __restrict__ qcw, const float* __restrict__ qfw,
                                                   ushort_t* __restrict__ Wb){
    int i = blockIdx.x*256 + threadIdx.x;   // 0 .. 163839
    int mat = i >> 14;
    int r = i & 16383;
    float v;
    if (mat < 4)      v = pcw[i];
    else if (mat == 4) v = pfw[r];
    else if (mat < 9)  v = qcw[i - 5*16384];
    else               v = qfw[r];
    Wb[i] = f2bf(v);
}

// ---------------- MFMA conv: D[oc][col] = sum_c W[oc][c] * pre(in[col][c]) ----------------
// A-operand = W (M=oc), B-operand = activations (N=col). D frag: 4 regs = 4 consecutive oc
// at one col -> packed 8B stores into [col][oc] layout. BN-stat partials fused in epilogue.
template<int PRE>
__global__ __launch_bounds__(256) void conv_mfma(const ushort_t* __restrict__ in, ushort_t* __restrict__ out,
                                                 const ushort_t* __restrict__ Wb, const float* __restrict__ scsh,
                                                 float* __restrict__ pb){
    int tid = threadIdx.x;
    int w = tid >> 6, l = tid & 63;
    int l15 = l & 15, l4 = l >> 4;
    int oc0 = (w & 1) << 6;                         // waves 0,2 -> oc 0..63 ; 1,3 -> 64..127
    long col0 = ((long)blockIdx.x << 7) + ((long)(w >> 1) << 6);   // col half per wave

    f32x4 acc[4][4] = {};                           // [mblk=oc][nblk=col]
    #pragma unroll
    for (int ks=0; ks<4; ks++){
        int kl = ks*32 + l4*8;                      // this lane's k base (8 contiguous k)
        s16x8 af[4];
        #pragma unroll
        for (int m=0;m<4;m++)
            af[m] = *(const s16x8*)(Wb + (oc0 + m*16 + l15)*C_ + kl);
        float sc[8], sh[8];
        if (PRE){
            const float4* sp = (const float4*)(scsh + kl*2);
            float4 s0 = sp[0], s1 = sp[1], s2 = sp[2], s3 = sp[3];
            sc[0]=s0.x; sh[0]=s0.y; sc[1]=s0.z; sh[1]=s0.w;
            sc[2]=s1.x; sh[2]=s1.y; sc[3]=s1.z; sh[3]=s1.w;
            sc[4]=s2.x; sh[4]=s2.y; sc[5]=s2.z; sh[5]=s2.w;
            sc[6]=s3.x; sh[6]=s3.y; sc[7]=s3.z; sh[7]=s3.w;
        }
        s16x8 bfr[4];
        #pragma unroll
        for (int n=0;n<4;n++){
            s16x8 v = *(const s16x8*)(in + (col0 + n*16 + l15)*C_ + kl);
            if (PRE){
                #pragma unroll
                for (int e=0;e<8;e++){
                    float f = bf2f((ushort_t)v[e]);
                    f = gelu_f(fmaf(f, sc[e], sh[e]));
                    v[e] = (short)f2bf(f);
                }
            }
            bfr[n] = v;
        }
        #pragma unroll
        for (int m=0;m<4;m++)
            #pragma unroll
            for (int n=0;n<4;n++)
                acc[m][n] = __builtin_amdgcn_mfma_f32_16x16x32_bf16(af[m], bfr[n], acc[m][n], 0, 0, 0);
    }

    __syncthreads();   // in-place safety: all waves' input loads complete before any store

    #pragma unroll
    for (int n=0;n<4;n++){
        long cadr = (col0 + n*16 + l15)*C_;
        #pragma unroll
        for (int m=0;m<4;m++){
            f32x4 a = acc[m][n];
            uint2 st;
            st.x = (((uint32)f2bf(a[1]))<<16) | f2bf(a[0]);
            st.y = (((uint32)f2bf(a[3]))<<16) | f2bf(a[2]);
            *(uint2*)(out + cadr + oc0 + m*16 + l4*4) = st;
        }
    }

    // BN-stat partials: per-oc sum & sumsq over this block's 128 cols
    __shared__ float sL[4][64], qL[4][64];
    #pragma unroll
    for (int m=0;m<4;m++){
        #pragma unroll
        for (int r=0;r<4;r++){
            float a0=acc[m][0][r], a1=acc[m][1][r], a2=acc[m][2][r], a3=acc[m][3][r];
            float s = a0+a1+a2+a3;
            float q = a0*a0+a1*a1+a2*a2+a3*a3;
            #pragma unroll
            for (int off=1; off<16; off<<=1){
                s += __shfl_xor(s, off, 64);
                q += __shfl_xor(q, off, 64);
            }
            if (l15 == 0){
                sL[w][m*16 + l4*4 + r] = s;
                qL[w][m*16 + l4*4 + r] = q;
            }
        }
    }
    __syncthreads();
    if (tid < 128){
        int half = tid >> 6, rel = tid & 63;
        float s = sL[half][rel] + sL[half+2][rel];
        float q = qL[half][rel] + qL[half+2][rel];
        pb[(long)blockIdx.x*256 + tid]       = s;
        pb[(long)blockIdx.x*256 + 128 + tid] = q;
    }
}

// ---------------- reduce per-block partials -> (scale, shift) ----------------
__global__ __launch_bounds__(256) void reduce_fin_kernel(const float* __restrict__ pb, float* __restrict__ scsh,
                                                         const float* __restrict__ g, const float* __restrict__ bb,
                                                         float inv_cnt, int nb){
    int oc = blockIdx.x;    // 128 blocks
    float s=0.f, q=0.f;
    for (int b=threadIdx.x; b<nb; b+=256){
        s += pb[(long)b*256 + oc];
        q += pb[(long)b*256 + 128 + oc];
    }
    __shared__ float ls[256], lq[256];
    ls[threadIdx.x]=s; lq[threadIdx.x]=q;
    __syncthreads();
    #pragma unroll
    for (int st_=128; st_>0; st_>>=1){
        if (threadIdx.x < st_){ ls[threadIdx.x]+=ls[threadIdx.x+st_]; lq[threadIdx.x]+=lq[threadIdx.x+st_]; }
        __syncthreads();
    }
    if (threadIdx.x==0){
        float mean = ls[0]*inv_cnt;
        float var  = lq[0]*inv_cnt - mean*mean;
        float sc   = g[oc]*rsqrtf(var + EPS_);
        scsh[oc*2+0] = sc;
        scsh[oc*2+1] = bb[oc] - mean*sc;
    }
}

// ---------------- A = gelu(bn(T) + A) ----------------
__global__ __launch_bounds__(256) void resid_kernel(ushort_t* __restrict__ A, const ushort_t* __restrict__ T,
                                                    const float* __restrict__ scsh){
    __shared__ float ss[256];
    ss[threadIdx.x] = scsh[threadIdx.x];
    __syncthreads();
    long t = (long)blockIdx.x*256 + threadIdx.x;
    long base = t*8;
    int c0 = (int)(base & (C_-1));
    us8 av = *(const us8*)(A+base);
    us8 tv = *(const us8*)(T+base);
    us8 r;
    #pragma unroll
    for (int j=0;j<8;j++){
        float sc = ss[(c0+j)*2], sh = ss[(c0+j)*2+1];
        float f = gelu_f(fmaf(bf2f(tv[j]), sc, sh) + bf2f(av[j]));
        r[j] = f2bf(f);
    }
    *(us8*)(A+base) = r;
}

// ---------------- max over K: A1 (bs,k,c) -> A2 (bs,c) ----------------
__global__ __launch_bounds__(256) void pool_kernel(const ushort_t* __restrict__ A1, ushort_t* __restrict__ A2){
    long p  = (long)blockIdx.x*256 + threadIdx.x;    // 8192*64
    long bs = p >> 6;
    int  c0 = ((int)p & 63)*2;
    const ushort_t* base = A1 + (bs*K_)*(long)C_ + c0;
    float m0 = -1e30f, m1 = -1e30f;
    #pragma unroll
    for (int k=0;k<K_;k++){
        uint32 v = *(const uint32*)(base + (long)k*C_);
        m0 = fmaxf(m0, bf2f((ushort_t)(v & 0xFFFFu)));
        m1 = fmaxf(m1, bf2f((ushort_t)(v >> 16)));
    }
    uint32 o = (((uint32)f2bf(m1))<<16) | f2bf(m0);
    *(uint32*)(A2 + bs*C_ + c0) = o;
}

// ---------------- final output: y[b][c][s] = A2[b*S+s][c] ----------------
__global__ __launch_bounds__(256) void out_kernel(const ushort_t* __restrict__ A2, float* __restrict__ y){
    long o = (long)blockIdx.x*256 + threadIdx.x;     // B*C*S
    int s = (int)(o & (S_-1));
    int c = (int)((o >> 10) & (C_-1));
    int b = (int)(o >> 17);
    y[o] = bf2f(A2[((long)(b*S_ + s))*C_ + c]);
}

// ---------------- host side ----------------
static void run_ext(ushort_t* A, ushort_t* Bb, long ncol,
                    const ushort_t* Wb5, const float* g, const float* b,
                    const float* fg, const float* fb,
                    float* pb, float* scsh, float inv_cnt, hipStream_t stream){
    int nb    = (int)(ncol/128);
    int rgrid = (int)((ncol*(long)C_)/(256*8));
    const ushort_t* W[5]  = {Wb5, Wb5+C_*C_, Wb5+2*C_*C_, Wb5+3*C_*C_, Wb5+4*C_*C_};
    const float* G[5]  = {g, g+C_, g+2*C_, g+3*C_, fg};
    const float* Bv[5] = {b, b+C_, b+2*C_, b+3*C_, fb};

    // res block 0
    conv_mfma<0><<<nb,256,0,stream>>>(A, Bb, W[0], nullptr, pb);
    reduce_fin_kernel<<<128,256,0,stream>>>(pb, scsh+0*256, G[0], Bv[0], inv_cnt, nb);
    conv_mfma<1><<<nb,256,0,stream>>>(Bb, Bb, W[1], scsh+0*256, pb);
    reduce_fin_kernel<<<128,256,0,stream>>>(pb, scsh+1*256, G[1], Bv[1], inv_cnt, nb);
    resid_kernel<<<rgrid,256,0,stream>>>(A, Bb, scsh+1*256);
    // res block 1
    conv_mfma<0><<<nb,256,0,stream>>>(A, Bb, W[2], nullptr, pb);
    reduce_fin_kernel<<<128,256,0,stream>>>(pb, scsh+2*256, G[2], Bv[2], inv_cnt, nb);
    conv_mfma<1><<<nb,256,0,stream>>>(Bb, Bb, W[3], scsh+2*256, pb);
    reduce_fin_kernel<<<128,256,0,stream>>>(pb, scsh+3*256, G[3], Bv[3], inv_cnt, nb);
    resid_kernel<<<rgrid,256,0,stream>>>(A, Bb, scsh+3*256);
    // final ffn
    conv_mfma<0><<<nb,256,0,stream>>>(A, Bb, W[4], nullptr, pb);
    reduce_fin_kernel<<<128,256,0,stream>>>(pb, scsh+4*256, G[4], Bv[4], inv_cnt, nb);
    resid_kernel<<<rgrid,256,0,stream>>>(A, Bb, scsh+4*256);
}

extern "C" void kernel_launch(void* const* d_in, const int* in_sizes, int n_in,
                              void* d_out, int out_size, void* d_ws, size_t ws_size,
                              hipStream_t stream){
    const float* xyz        = (const float*)d_in[0];
    const float* x          = (const float*)d_in[1];
    const int*   fps        = (const int*)d_in[2];
    const float* pre_conv_w = (const float*)d_in[3];
    const float* pre_bn_g   = (const float*)d_in[4];
    const float* pre_bn_b   = (const float*)d_in[5];
    const float* pre_ffn_w  = (const float*)d_in[6];
    const float* pre_ffn_g  = (const float*)d_in[7];
    const float* pre_ffn_b  = (const float*)d_in[8];
    const float* pos_conv_w = (const float*)d_in[9];
    const float* pos_bn_g   = (const float*)d_in[10];
    const float* pos_bn_b   = (const float*)d_in[11];
    const float* pos_ffn_w  = (const float*)d_in[12];
    const float* pos_ffn_g  = (const float*)d_in[13];
    const float* pos_ffn_b  = (const float*)d_in[14];

    float* out_xyz = (float*)d_out;
    float* out_y   = (float*)d_out + (long)B_*S_*3;

    // ws layout (bytes), lifetimes disjoint where overlapped:
    //   0        scsh   (10240)
    //   10240    Wb     (327680)              -> 337920
    //   337920   idx (1MB, knn/build) THEN pb (2MB, convs)   -> 2435072
    //   2435072  xT (8MB, until build) THEN A2(2MB)+B2(2MB)  -> 10823680
    //   10823680 A1 (64MB)                    -> 77932544
    //   77932544 B1 (64MB)                    -> 145041408
    char* ws = (char*)d_ws;
    float*    scsh  = (float*)(ws + 0);
    ushort_t* Wb    = (ushort_t*)(ws + 10240);
    int*      idx   = (int*)(ws + 337920);
    float*    pb    = (float*)(ws + 337920);
    float*    xT    = (float*)(ws + 2435072);
    ushort_t* A2    = (ushort_t*)(ws + 2435072);
    ushort_t* B2    = (ushort_t*)(ws + 4532224);
    ushort_t* A1    = (ushort_t*)(ws + 10823680);
    ushort_t* B1    = (ushort_t*)(ws + 77932544);
    (void)in_sizes; (void)n_in; (void)out_size; (void)ws_size;

    wcvt_kernel<<<640,256,0,stream>>>(pre_conv_w, pre_ffn_w, pos_conv_w, pos_ffn_w, Wb);
    transpose_kernel<<<B_*(N_/64),256,0,stream>>>(x, xT);
    knn_kernel<<<B_*S_,256,0,stream>>>(xyz, fps, idx, out_xyz);
    build_kernel<<<NCOL1/256,256,0,stream>>>(xT, fps, idx, A1);

    run_ext(A1, B1, NCOL1, Wb, pre_bn_g, pre_bn_b, pre_ffn_g, pre_ffn_b,
            pb, scsh, 1.0f/(float)NCOL1, stream);

    pool_kernel<<<(NCOL2*64)/256,256,0,stream>>>(A1, A2);

    run_ext(A2, B2, NCOL2, Wb + 5*C_*C_, pos_bn_g, pos_bn_b, pos_ffn_g, pos_ffn_b,
            pb, scsh + 5*256, 1.0f/(float)NCOL2, stream);

    out_kernel<<<(B_*C_*S_)/256,256,0,stream>>>(A2, out_y);
}

// Round 3
// 811.037 us; speedup vs baseline: 5.4169x; 1.2327x over previous
//
#include <hip/hip_runtime.h>
#include <math.h>

typedef unsigned short ushort_t;
typedef unsigned long long u64;
typedef unsigned int uint32;

#define B_ 8
#define N_ 4096
#define S_ 1024
#define K_ 32
#define C_ 128
#define NCOL1 (B_*S_*K_)   // 262144
#define NCOL2 (B_*S_)      // 8192
#define EPS_ 1e-5f

typedef ushort_t us8 __attribute__((ext_vector_type(8)));
typedef short s16x8 __attribute__((ext_vector_type(8)));
typedef float f32x4 __attribute__((ext_vector_type(4)));

__device__ __forceinline__ float bf2f(ushort_t u){ return __uint_as_float(((uint32)u)<<16); }
__device__ __forceinline__ ushort_t f2bf(float f){
    uint32 x = __float_as_uint(f);
    return (ushort_t)((x + 0x7FFFu + ((x>>16)&1u)) >> 16);
}
__device__ __forceinline__ float gelu_f(float v){
    return 0.5f*v*(1.0f + erff(v*0.70710678118654752f));
}
__device__ __forceinline__ u64 shfl_xor_u64(u64 v, int m){
    int lo = __shfl_xor((int)(v & 0xFFFFFFFFull), m, 64);
    int hi = __shfl_xor((int)(v >> 32), m, 64);
    return (((u64)(uint32)hi) << 32) | (uint32)lo;
}

// ---------------- transpose x (B,64,N) -> xT (B,N,64) ----------------
__global__ __launch_bounds__(256) void transpose_kernel(const float* __restrict__ x, float* __restrict__ xT){
    __shared__ float t[64][65];
    int b  = blockIdx.x >> 6;
    int n0 = (blockIdx.x & 63) * 64;
    int tx = threadIdx.x & 63, ty = threadIdx.x >> 6;
    #pragma unroll
    for (int i=0;i<16;i++){
        int c = i*4 + ty;
        t[c][tx] = x[((long)(b*64 + c))*N_ + n0 + tx];
    }
    __syncthreads();
    #pragma unroll
    for (int i=0;i<16;i++){
        int n = i*4 + ty;
        xT[((long)(b*N_ + n0 + n))*64 + tx] = t[tx][n];
    }
}

// ---------------- KNN via 2-level radix select (exact top-32 set, sorted output) ----------------
__global__ __launch_bounds__(256) void knn_kernel(const float* __restrict__ xyz, const int* __restrict__ fps,
                                                  int* __restrict__ idxg, float* __restrict__ newxyz){
    __shared__ uint32 hist[4096];      // 16 KB
    __shared__ u64    cand[4096];      // 32 KB (worst-case tie class)
    __shared__ u64    out_keys[64];
    __shared__ uint32 csum[256];
    __shared__ uint32 wtot[4];
    __shared__ uint32 shv[6];          // 0:b1 1:cl1 2:b2 3:cl2 4:sel 5:cand

    int tid = threadIdx.x;
    int wv = tid >> 6, l = tid & 63;
    int bs = blockIdx.x;
    int b  = bs >> 10;
    int qi = fps[bs];
    const float* qb = xyz + ((long)b*N_ + qi)*3;
    float qx = qb[0], qy = qb[1], qz = qb[2];
    if (tid < 3) newxyz[(long)bs*3 + tid] = qb[tid];
    const float* xb = xyz + (long)b*N_*3;

    for (int i=tid;i<4096;i+=256) hist[i]=0;
    if (tid < 6) shv[tid]=0;
    __syncthreads();

    // pass 1: distances (kept in regs) + level-1 histogram (float bits 31..20)
    uint32 dbits[16];
    #pragma unroll
    for (int i=0;i<16;i++){
        int n = i*256 + tid;
        float dx = xb[n*3+0]-qx, dy = xb[n*3+1]-qy, dz = xb[n*3+2]-qz;
        float d = dx*dx + dy*dy + dz*dz;
        dbits[i] = __float_as_uint(d);
        atomicAdd(&hist[dbits[i]>>20], 1u);
    }
    __syncthreads();

    // scan level 1, find bin of rank 31
    uint32 h[16]; uint32 csumv = 0;
    #pragma unroll
    for (int i=0;i<16;i++){ h[i]=hist[tid*16+i]; csumv += h[i]; }
    {
        uint32 sc = csumv;
        #pragma unroll
        for (int off=1; off<64; off<<=1){
            uint32 o = __shfl_up(sc, off, 64);
            if (l >= off) sc += o;
        }
        if (l==63) wtot[wv]=sc;
        csum[tid]=sc;
        __syncthreads();
        uint32 base=0;
        for (int w2=0; w2<wv; w2++) base += wtot[w2];
        uint32 cum = base + csum[tid] - csumv;       // exclusive prefix
        #pragma unroll
        for (int i=0;i<16;i++){
            if (cum <= 31u && 31u < cum + h[i]){ shv[0]=(uint32)(tid*16+i); shv[1]=cum; }
            cum += h[i];
        }
    }
    __syncthreads();
    uint32 b1 = shv[0], cl1 = shv[1];

    // pass 2: level-2 histogram (bits 19..8) within bin b1
    for (int i=tid;i<4096;i+=256) hist[i]=0;
    __syncthreads();
    #pragma unroll
    for (int i=0;i<16;i++){
        uint32 u = dbits[i];
        if ((u>>20)==b1) atomicAdd(&hist[(u>>8)&0xFFFu], 1u);
    }
    __syncthreads();

    uint32 r2 = 31u - cl1;
    csumv = 0;
    #pragma unroll
    for (int i=0;i<16;i++){ h[i]=hist[tid*16+i]; csumv += h[i]; }
    {
        uint32 sc = csumv;
        #pragma unroll
        for (int off=1; off<64; off<<=1){
            uint32 o = __shfl_up(sc, off, 64);
            if (l >= off) sc += o;
        }
        if (l==63) wtot[wv]=sc;
        csum[tid]=sc;
        __syncthreads();
        uint32 base=0;
        for (int w2=0; w2<wv; w2++) base += wtot[w2];
        uint32 cum = base + csum[tid] - csumv;
        #pragma unroll
        for (int i=0;i<16;i++){
            if (cum <= r2 && r2 < cum + h[i]){ shv[2]=(uint32)(tid*16+i); shv[3]=cum; }
            cum += h[i];
        }
    }
    __syncthreads();
    uint32 b2 = shv[2], cl2 = shv[3];
    uint32 nless = cl1 + cl2;

    // pass 3: collect sure-winners and boundary candidates
    #pragma unroll
    for (int i=0;i<16;i++){
        uint32 u = dbits[i];
        int n = i*256 + tid;
        uint32 bb1 = u >> 20;
        if (bb1 > b1) continue;
        u64 key = (((u64)u)<<32) | (uint32)n;
        if (bb1 < b1){
            uint32 p = atomicAdd(&shv[4],1u); out_keys[p] = key;
        } else {
            uint32 bb2 = (u>>8)&0xFFFu;
            if (bb2 < b2){ uint32 p = atomicAdd(&shv[4],1u); out_keys[p] = key; }
            else if (bb2 == b2){ uint32 p = atomicAdd(&shv[5],1u); cand[p] = key; }
        }
    }
    __syncthreads();

    // wave 0: pick `need` smallest from cand, then bitonic-sort all 32 by (dist,idx)
    if (wv == 0){
        uint32 cb   = shv[5];
        uint32 need = 32u - nless;
        for (uint32 r=0; r<need; r++){
            u64 lmin = ~0ull;
            for (uint32 s=l; s<cb; s+=64){ u64 kk = cand[s]; if (kk < lmin) lmin = kk; }
            #pragma unroll
            for (int off=32; off>=1; off>>=1){
                u64 o = shfl_xor_u64(lmin, off);
                if (o < lmin) lmin = o;
            }
            for (uint32 s=l; s<cb; s+=64){ if (cand[s]==lmin) cand[s] = ~0ull; }
            if (l==0) out_keys[nless + r] = lmin;
        }
        u64 key = (l < 32) ? out_keys[l] : ~0ull;
        #pragma unroll
        for (uint32 k=2; k<=64; k<<=1){
            bool dir = ((l & k)==0);
            #pragma unroll
            for (uint32 j=k>>1; j>=1; j>>=1){
                u64 o = shfl_xor_u64(key, j);
                bool lower = ((l & j)==0);
                u64 mn = (key < o) ? key : o;
                u64 mx = (key < o) ? o : key;
                key = (lower == dir) ? mn : mx;
            }
        }
        if (l < 32) idxg[(long)bs*K_ + l] = (int)(key & 0xFFFFFFFFull);
    }
}

// ---------------- build features: A[col][c], col=(b*S+s)*K+k ----------------
__global__ __launch_bounds__(256) void build_kernel(const float* __restrict__ xT, const int* __restrict__ fps,
                                                    const int* __restrict__ idxg, ushort_t* __restrict__ A){
    long col = (long)blockIdx.x*256 + threadIdx.x;
    long bs  = col >> 5;
    int  b   = (int)(bs >> 10);
    int  n   = idxg[col];
    int  cn  = fps[bs];
    const float4* pr = (const float4*)(xT + ((long)b*N_ + n )*64);
    const float4* cr = (const float4*)(xT + ((long)b*N_ + cn)*64);
    ushort_t* op = A + col*C_;
    #pragma unroll
    for (int j=0;j<16;j++){
        float4 p = pr[j], c = cr[j];
        uint2 d, e;
        d.x = (((uint32)f2bf(p.y-c.y))<<16) | f2bf(p.x-c.x);
        d.y = (((uint32)f2bf(p.w-c.w))<<16) | f2bf(p.z-c.z);
        e.x = (((uint32)f2bf(c.y))<<16) | f2bf(c.x);
        e.y = (((uint32)f2bf(c.w))<<16) | f2bf(c.z);
        *(uint2*)(op + j*4)      = d;
        *(uint2*)(op + 64 + j*4) = e;
    }
}

// ---------------- convert all 10 weight matrices f32 -> bf16 ----------------
__global__ __launch_bounds__(256) void wcvt_kernel(const float* __restrict__ pcw, const float* __restrict__ pfw,
                                                   const float* __restrict__ qcw, const float* __restrict__ qfw,
                                                   ushort_t* __restrict__ Wb){
    int i = blockIdx.x*256 + threadIdx.x;   // 0 .. 163839
    int mat = i >> 14;
    int r = i & 16383;
    float v;
    if (mat < 4)      v = pcw[i];
    else if (mat == 4) v = pfw[r];
    else if (mat < 9)  v = qcw[i - 5*16384];
    else               v = qfw[r];
    Wb[i] = f2bf(v);
}

// ---------------- MFMA conv: D[oc][col] = sum_c W[oc][c] * pre(in[col][c]) ----------------
template<int PRE>
__global__ __launch_bounds__(256) void conv_mfma(const ushort_t* __restrict__ in, ushort_t* __restrict__ out,
                                                 const ushort_t* __restrict__ Wb, const float* __restrict__ scsh,
                                                 float* __restrict__ pb){
    int tid = threadIdx.x;
    int w = tid >> 6, l = tid & 63;
    int l15 = l & 15, l4 = l >> 4;
    int oc0 = (w & 1) << 6;                         // waves 0,2 -> oc 0..63 ; 1,3 -> 64..127
    long col0 = ((long)blockIdx.x << 7) + ((long)(w >> 1) << 6);   // col half per wave

    f32x4 acc[4][4] = {};                           // [mblk=oc][nblk=col]
    #pragma unroll
    for (int ks=0; ks<4; ks++){
        int kl = ks*32 + l4*8;                      // this lane's k base (8 contiguous k)
        s16x8 af[4];
        #pragma unroll
        for (int m=0;m<4;m++)
            af[m] = *(const s16x8*)(Wb + (oc0 + m*16 + l15)*C_ + kl);
        float sc[8], sh[8];
        if (PRE){
            const float4* sp = (const float4*)(scsh + kl*2);
            float4 s0 = sp[0], s1 = sp[1], s2 = sp[2], s3 = sp[3];
            sc[0]=s0.x; sh[0]=s0.y; sc[1]=s0.z; sh[1]=s0.w;
            sc[2]=s1.x; sh[2]=s1.y; sc[3]=s1.z; sh[3]=s1.w;
            sc[4]=s2.x; sh[4]=s2.y; sc[5]=s2.z; sh[5]=s2.w;
            sc[6]=s3.x; sh[6]=s3.y; sc[7]=s3.z; sh[7]=s3.w;
        }
        s16x8 bfr[4];
        #pragma unroll
        for (int n=0;n<4;n++){
            s16x8 v = *(const s16x8*)(in + (col0 + n*16 + l15)*C_ + kl);
            if (PRE){
                #pragma unroll
                for (int e=0;e<8;e++){
                    float f = bf2f((ushort_t)v[e]);
                    f = gelu_f(fmaf(f, sc[e], sh[e]));
                    v[e] = (short)f2bf(f);
                }
            }
            bfr[n] = v;
        }
        #pragma unroll
        for (int m=0;m<4;m++)
            #pragma unroll
            for (int n=0;n<4;n++)
                acc[m][n] = __builtin_amdgcn_mfma_f32_16x16x32_bf16(af[m], bfr[n], acc[m][n], 0, 0, 0);
    }

    __syncthreads();   // in-place safety: all waves' input loads complete before any store

    #pragma unroll
    for (int n=0;n<4;n++){
        long cadr = (col0 + n*16 + l15)*C_;
        #pragma unroll
        for (int m=0;m<4;m++){
            f32x4 a = acc[m][n];
            uint2 st;
            st.x = (((uint32)f2bf(a[1]))<<16) | f2bf(a[0]);
            st.y = (((uint32)f2bf(a[3]))<<16) | f2bf(a[2]);
            *(uint2*)(out + cadr + oc0 + m*16 + l4*4) = st;
        }
    }

    // BN-stat partials: per-oc sum & sumsq over this block's 128 cols
    __shared__ float sL[4][64], qL[4][64];
    #pragma unroll
    for (int m=0;m<4;m++){
        #pragma unroll
        for (int r=0;r<4;r++){
            float a0=acc[m][0][r], a1=acc[m][1][r], a2=acc[m][2][r], a3=acc[m][3][r];
            float s = a0+a1+a2+a3;
            float q = a0*a0+a1*a1+a2*a2+a3*a3;
            #pragma unroll
            for (int off=1; off<16; off<<=1){
                s += __shfl_xor(s, off, 64);
                q += __shfl_xor(q, off, 64);
            }
            if (l15 == 0){
                sL[w][m*16 + l4*4 + r] = s;
                qL[w][m*16 + l4*4 + r] = q;
            }
        }
    }
    __syncthreads();
    if (tid < 128){
        int half = tid >> 6, rel = tid & 63;
        float s = sL[half][rel] + sL[half+2][rel];
        float q = qL[half][rel] + qL[half+2][rel];
        pb[(long)blockIdx.x*256 + tid]       = s;
        pb[(long)blockIdx.x*256 + 128 + tid] = q;
    }
}

// ---------------- reduce per-block partials -> (scale, shift) ----------------
__global__ __launch_bounds__(256) void reduce_fin_kernel(const float* __restrict__ pb, float* __restrict__ scsh,
                                                         const float* __restrict__ g, const float* __restrict__ bb,
                                                         float inv_cnt, int nb){
    int oc = blockIdx.x;    // 128 blocks
    float s=0.f, q=0.f;
    for (int b=threadIdx.x; b<nb; b+=256){
        s += pb[(long)b*256 + oc];
        q += pb[(long)b*256 + 128 + oc];
    }
    __shared__ float ls[256], lq[256];
    ls[threadIdx.x]=s; lq[threadIdx.x]=q;
    __syncthreads();
    #pragma unroll
    for (int st_=128; st_>0; st_>>=1){
        if (threadIdx.x < st_){ ls[threadIdx.x]+=ls[threadIdx.x+st_]; lq[threadIdx.x]+=lq[threadIdx.x+st_]; }
        __syncthreads();
    }
    if (threadIdx.x==0){
        float mean = ls[0]*inv_cnt;
        float var  = lq[0]*inv_cnt - mean*mean;
        float sc   = g[oc]*rsqrtf(var + EPS_);
        scsh[oc*2+0] = sc;
        scsh[oc*2+1] = bb[oc] - mean*sc;
    }
}

// ---------------- A = gelu(bn(T) + A) ----------------
__global__ __launch_bounds__(256) void resid_kernel(ushort_t* __restrict__ A, const ushort_t* __restrict__ T,
                                                    const float* __restrict__ scsh){
    __shared__ float ss[256];
    ss[threadIdx.x] = scsh[threadIdx.x];
    __syncthreads();
    long t = (long)blockIdx.x*256 + threadIdx.x;
    long base = t*8;
    int c0 = (int)(base & (C_-1));
    us8 av = *(const us8*)(A+base);
    us8 tv = *(const us8*)(T+base);
    us8 r;
    #pragma unroll
    for (int j=0;j<8;j++){
        float sc = ss[(c0+j)*2], sh = ss[(c0+j)*2+1];
        float f = gelu_f(fmaf(bf2f(tv[j]), sc, sh) + bf2f(av[j]));
        r[j] = f2bf(f);
    }
    *(us8*)(A+base) = r;
}

// ---------------- max over K: A1 (bs,k,c) -> A2 (bs,c) ----------------
__global__ __launch_bounds__(256) void pool_kernel(const ushort_t* __restrict__ A1, ushort_t* __restrict__ A2){
    long p  = (long)blockIdx.x*256 + threadIdx.x;    // 8192*64
    long bs = p >> 6;
    int  c0 = ((int)p & 63)*2;
    const ushort_t* base = A1 + (bs*K_)*(long)C_ + c0;
    float m0 = -1e30f, m1 = -1e30f;
    #pragma unroll
    for (int k=0;k<K_;k++){
        uint32 v = *(const uint32*)(base + (long)k*C_);
        m0 = fmaxf(m0, bf2f((ushort_t)(v & 0xFFFFu)));
        m1 = fmaxf(m1, bf2f((ushort_t)(v >> 16)));
    }
    uint32 o = (((uint32)f2bf(m1))<<16) | f2bf(m0);
    *(uint32*)(A2 + bs*C_ + c0) = o;
}

// ---------------- final output: y[b][c][s] = A2[b*S+s][c] ----------------
__global__ __launch_bounds__(256) void out_kernel(const ushort_t* __restrict__ A2, float* __restrict__ y){
    long o = (long)blockIdx.x*256 + threadIdx.x;     // B*C*S
    int s = (int)(o & (S_-1));
    int c = (int)((o >> 10) & (C_-1));
    int b = (int)(o >> 17);
    y[o] = bf2f(A2[((long)(b*S_ + s))*C_ + c]);
}

// ---------------- host side ----------------
static void run_ext(ushort_t* A, ushort_t* Bb, long ncol,
                    const ushort_t* Wb5, const float* g, const float* b,
                    const float* fg, const float* fb,
                    float* pb, float* scsh, float inv_cnt, hipStream_t stream){
    int nb    = (int)(ncol/128);
    int rgrid = (int)((ncol*(long)C_)/(256*8));
    const ushort_t* W[5]  = {Wb5, Wb5+C_*C_, Wb5+2*C_*C_, Wb5+3*C_*C_, Wb5+4*C_*C_};
    const float* G[5]  = {g, g+C_, g+2*C_, g+3*C_, fg};
    const float* Bv[5] = {b, b+C_, b+2*C_, b+3*C_, fb};

    // res block 0
    conv_mfma<0><<<nb,256,0,stream>>>(A, Bb, W[0], nullptr, pb);
    reduce_fin_kernel<<<128,256,0,stream>>>(pb, scsh+0*256, G[0], Bv[0], inv_cnt, nb);
    conv_mfma<1><<<nb,256,0,stream>>>(Bb, Bb, W[1], scsh+0*256, pb);
    reduce_fin_kernel<<<128,256,0,stream>>>(pb, scsh+1*256, G[1], Bv[1], inv_cnt, nb);
    resid_kernel<<<rgrid,256,0,stream>>>(A, Bb, scsh+1*256);
    // res block 1
    conv_mfma<0><<<nb,256,0,stream>>>(A, Bb, W[2], nullptr, pb);
    reduce_fin_kernel<<<128,256,0,stream>>>(pb, scsh+2*256, G[2], Bv[2], inv_cnt, nb);
    conv_mfma<1><<<nb,256,0,stream>>>(Bb, Bb, W[3], scsh+2*256, pb);
    reduce_fin_kernel<<<128,256,0,stream>>>(pb, scsh+3*256, G[3], Bv[3], inv_cnt, nb);
    resid_kernel<<<rgrid,256,0,stream>>>(A, Bb, scsh+3*256);
    // final ffn
    conv_mfma<0><<<nb,256,0,stream>>>(A, Bb, W[4], nullptr, pb);
    reduce_fin_kernel<<<128,256,0,stream>>>(pb, scsh+4*256, G[4], Bv[4], inv_cnt, nb);
    resid_kernel<<<rgrid,256,0,stream>>>(A, Bb, scsh+4*256);
}

extern "C" void kernel_launch(void* const* d_in, const int* in_sizes, int n_in,
                              void* d_out, int out_size, void* d_ws, size_t ws_size,
                              hipStream_t stream){
    const float* xyz        = (const float*)d_in[0];
    const float* x          = (const float*)d_in[1];
    const int*   fps        = (const int*)d_in[2];
    const float* pre_conv_w = (const float*)d_in[3];
    const float* pre_bn_g   = (const float*)d_in[4];
    const float* pre_bn_b   = (const float*)d_in[5];
    const float* pre_ffn_w  = (const float*)d_in[6];
    const float* pre_ffn_g  = (const float*)d_in[7];
    const float* pre_ffn_b  = (const float*)d_in[8];
    const float* pos_conv_w = (const float*)d_in[9];
    const float* pos_bn_g   = (const float*)d_in[10];
    const float* pos_bn_b   = (const float*)d_in[11];
    const float* pos_ffn_w  = (const float*)d_in[12];
    const float* pos_ffn_g  = (const float*)d_in[13];
    const float* pos_ffn_b  = (const float*)d_in[14];

    float* out_xyz = (float*)d_out;
    float* out_y   = (float*)d_out + (long)B_*S_*3;

    // ws layout (bytes), lifetimes disjoint where overlapped:
    //   0        scsh   (10240)
    //   10240    Wb     (327680)              -> 337920
    //   337920   idx (1MB, knn/build) THEN pb (2MB, convs)   -> 2435072
    //   2435072  xT (8MB, until build) THEN A2(2MB)+B2(2MB)  -> 10823680
    //   10823680 A1 (64MB)                    -> 77932544
    //   77932544 B1 (64MB)                    -> 145041408
    char* ws = (char*)d_ws;
    float*    scsh  = (float*)(ws + 0);
    ushort_t* Wb    = (ushort_t*)(ws + 10240);
    int*      idx   = (int*)(ws + 337920);
    float*    pb    = (float*)(ws + 337920);
    float*    xT    = (float*)(ws + 2435072);
    ushort_t* A2    = (ushort_t*)(ws + 2435072);
    ushort_t* B2    = (ushort_t*)(ws + 4532224);
    ushort_t* A1    = (ushort_t*)(ws + 10823680);
    ushort_t* B1    = (ushort_t*)(ws + 77932544);
    (void)in_sizes; (void)n_in; (void)out_size; (void)ws_size;

    wcvt_kernel<<<640,256,0,stream>>>(pre_conv_w, pre_ffn_w, pos_conv_w, pos_ffn_w, Wb);
    transpose_kernel<<<B_*(N_/64),256,0,stream>>>(x, xT);
    knn_kernel<<<B_*S_,256,0,stream>>>(xyz, fps, idx, out_xyz);
    build_kernel<<<NCOL1/256,256,0,stream>>>(xT, fps, idx, A1);

    run_ext(A1, B1, NCOL1, Wb, pre_bn_g, pre_bn_b, pre_ffn_g, pre_ffn_b,
            pb, scsh, 1.0f/(float)NCOL1, stream);

    pool_kernel<<<(NCOL2*64)/256,256,0,stream>>>(A1, A2);

    run_ext(A2, B2, NCOL2, Wb + 5*C_*C_, pos_bn_g, pos_bn_b, pos_ffn_g, pos_ffn_b,
            pb, scsh + 5*256, 1.0f/(float)NCOL2, stream);

    out_kernel<<<(B_*C_*S_)/256,256,0,stream>>>(A2, out_y);
}

// Round 5
// 695.951 us; speedup vs baseline: 6.3126x; 1.1654x over previous
//
#include <hip/hip_runtime.h>
#include <math.h>

typedef unsigned short ushort_t;
typedef unsigned long long u64;
typedef unsigned int uint32;

#define B_ 8
#define N_ 4096
#define S_ 1024
#define K_ 32
#define C_ 128
#define NCOL1 (B_*S_*K_)   // 262144
#define NCOL2 (B_*S_)      // 8192
#define EPS_ 1e-5f

typedef ushort_t us8 __attribute__((ext_vector_type(8)));
typedef short s16x8 __attribute__((ext_vector_type(8)));
typedef float f32x4 __attribute__((ext_vector_type(4)));

__device__ __forceinline__ float bf2f(ushort_t u){ return __uint_as_float(((uint32)u)<<16); }
__device__ __forceinline__ ushort_t f2bf(float f){
    uint32 x = __float_as_uint(f);
    return (ushort_t)((x + 0x7FFFu + ((x>>16)&1u)) >> 16);
}
// gelu with A&S 7.1.26 erf: |err| <= 1.5e-7, branchless, ~14 VALU ops
__device__ __forceinline__ float gelu_f(float v){
    float az = fabsf(v)*0.70710678118654752f;
    float t  = __builtin_amdgcn_rcpf(fmaf(0.3275911f, az, 1.0f));
    float p  = fmaf(fmaf(fmaf(fmaf(1.061405429f, t, -1.453152027f), t, 1.421413741f), t,
                   -0.284496736f), t, 0.254829592f)*t;
    float e  = __expf(-az*az);
    float er = fmaf(-p, e, 1.0f);                    // erf(|z|)
    float s  = (v < 0.0f) ? -er : er;
    return 0.5f*v*(1.0f+s);
}
__device__ __forceinline__ u64 shfl_xor_u64(u64 v, int m){
    int lo = __shfl_xor((int)(v & 0xFFFFFFFFull), m, 64);
    int hi = __shfl_xor((int)(v >> 32), m, 64);
    return (((u64)(uint32)hi) << 32) | (uint32)lo;
}

// ---------------- transpose x (B,64,N) -> xT (B,N,64) ----------------
__global__ __launch_bounds__(256) void transpose_kernel(const float* __restrict__ x, float* __restrict__ xT){
    __shared__ float t[64][65];
    int b  = blockIdx.x >> 6;
    int n0 = (blockIdx.x & 63) * 64;
    int tx = threadIdx.x & 63, ty = threadIdx.x >> 6;
    #pragma unroll
    for (int i=0;i<16;i++){
        int c = i*4 + ty;
        t[c][tx] = x[((long)(b*64 + c))*N_ + n0 + tx];
    }
    __syncthreads();
    #pragma unroll
    for (int i=0;i<16;i++){
        int n = i*4 + ty;
        xT[((long)(b*N_ + n0 + n))*64 + tx] = t[tx][n];
    }
}

// ---------------- KNN: 2-level radix select (1024/4096 bins), exact, low-LDS ----------------
__global__ __launch_bounds__(256) void knn_kernel(const float* __restrict__ xyz, const int* __restrict__ fps,
                                                  int* __restrict__ idxg, float* __restrict__ newxyz){
    __shared__ uint32 hist[4096];      // 16 KB (pass1 uses first 1024)
    __shared__ u64    cand[1024];      // 8 KB
    __shared__ u64    out_keys[64];
    __shared__ uint32 csum[256];
    __shared__ uint32 wtot[4];
    __shared__ uint32 shv[8];          // 0:b1 1:cl1 2:b2 3:cl2 4:sel 5:cand
    __shared__ u64    wred[4];
    __shared__ u64    winner;

    int tid = threadIdx.x;
    int wv = tid >> 6, l = tid & 63;
    int bs = blockIdx.x;
    int b  = bs >> 10;
    int qi = fps[bs];
    const float* qb = xyz + ((long)b*N_ + qi)*3;
    float qx = qb[0], qy = qb[1], qz = qb[2];
    if (tid < 3) newxyz[(long)bs*3 + tid] = qb[tid];
    const float* xb = xyz + (long)b*N_*3;

    for (int i=tid;i<1024;i+=256) hist[i]=0;
    if (tid < 8) shv[tid]=0;
    __syncthreads();

    // pass 1: distances (regs) + level-1 histogram (bits 30..21, 1024 bins)
    uint32 dbits[16];
    #pragma unroll
    for (int i=0;i<16;i++){
        int n = i*256 + tid;
        float dx = xb[n*3+0]-qx, dy = xb[n*3+1]-qy, dz = xb[n*3+2]-qz;
        float d = dx*dx + dy*dy + dz*dz;
        dbits[i] = __float_as_uint(d);
        atomicAdd(&hist[dbits[i]>>21], 1u);
    }
    __syncthreads();

    // scan level 1 (4 bins/thread), find bin of rank 31
    {
        uint32 h4[4]; uint32 csumv=0;
        #pragma unroll
        for (int i=0;i<4;i++){ h4[i]=hist[tid*4+i]; csumv+=h4[i]; }
        uint32 sc = csumv;
        #pragma unroll
        for (int off=1; off<64; off<<=1){ uint32 o=__shfl_up(sc,off,64); if (l>=off) sc+=o; }
        if (l==63) wtot[wv]=sc;
        csum[tid]=sc;
        __syncthreads();
        uint32 base=0;
        for (int w2=0; w2<wv; w2++) base += wtot[w2];
        uint32 cum = base + csum[tid] - csumv;
        #pragma unroll
        for (int i=0;i<4;i++){
            if (cum <= 31u && 31u < cum + h4[i]){ shv[0]=(uint32)(tid*4+i); shv[1]=cum; }
            cum += h4[i];
        }
    }
    __syncthreads();
    uint32 b1 = shv[0], cl1 = shv[1];

    // pass 2: level-2 histogram (bits 20..9, 4096 bins) within bin b1
    for (int i=tid;i<4096;i+=256) hist[i]=0;
    __syncthreads();
    #pragma unroll
    for (int i=0;i<16;i++){
        uint32 u = dbits[i];
        if ((u>>21)==b1) atomicAdd(&hist[(u>>9)&0xFFFu], 1u);
    }
    __syncthreads();

    uint32 r2 = 31u - cl1;
    {
        uint32 h[16]; uint32 csumv=0;
        #pragma unroll
        for (int i=0;i<16;i++){ h[i]=hist[tid*16+i]; csumv += h[i]; }
        uint32 sc = csumv;
        #pragma unroll
        for (int off=1; off<64; off<<=1){ uint32 o=__shfl_up(sc,off,64); if (l>=off) sc+=o; }
        if (l==63) wtot[wv]=sc;
        csum[tid]=sc;
        __syncthreads();
        uint32 base=0;
        for (int w2=0; w2<wv; w2++) base += wtot[w2];
        uint32 cum = base + csum[tid] - csumv;
        #pragma unroll
        for (int i=0;i<16;i++){
            if (cum <= r2 && r2 < cum + h[i]){ shv[2]=(uint32)(tid*16+i); shv[3]=cum; }
            cum += h[i];
        }
    }
    __syncthreads();
    uint32 b2 = shv[2], cl2 = shv[3];
    uint32 nless = cl1 + cl2;

    // pass 3: collect sure-winners + boundary candidates (guarded)
    #pragma unroll
    for (int i=0;i<16;i++){
        uint32 u = dbits[i];
        int n = i*256 + tid;
        uint32 bb1 = u >> 21;
        if (bb1 > b1) continue;
        u64 key = (((u64)u)<<32) | (uint32)n;
        if (bb1 < b1){
            uint32 p = atomicAdd(&shv[4],1u); out_keys[p] = key;
        } else {
            uint32 bb2 = (u>>9)&0xFFFu;
            if (bb2 < b2){ uint32 p = atomicAdd(&shv[4],1u); out_keys[p] = key; }
            else if (bb2 == b2){ uint32 p = atomicAdd(&shv[5],1u); if (p < 1024u) cand[p] = key; }
        }
    }
    __syncthreads();

    if (shv[5] > 1024u){
        // exact fallback (massive tie class): serial 32-round block argmin
        uint32 alive = 0xFFFFu;
        for (int r=0;r<K_;r++){
            u64 lmin = ~0ull;
            #pragma unroll
            for (int i=0;i<16;i++){
                u64 k = (((u64)dbits[i])<<32) | (uint32)(i*256+tid);
                if (((alive>>i)&1u) && k < lmin) lmin = k;
            }
            #pragma unroll
            for (int off=32; off>=1; off>>=1){
                u64 o = shfl_xor_u64(lmin, off);
                if (o < lmin) lmin = o;
            }
            if (l == 0) wred[wv] = lmin;
            __syncthreads();
            if (tid == 0){
                u64 m = wred[0];
                if (wred[1]<m) m=wred[1];
                if (wred[2]<m) m=wred[2];
                if (wred[3]<m) m=wred[3];
                winner = m;
                idxg[(long)bs*K_ + r] = (int)(m & 0xFFFFFFFFull);
            }
            __syncthreads();
            u64 w = winner;
            #pragma unroll
            for (int i=0;i<16;i++){
                u64 k = (((u64)dbits[i])<<32) | (uint32)(i*256+tid);
                if (k == w) alive &= ~(1u<<i);
            }
        }
    } else if (wv == 0){
        uint32 cb   = shv[5];
        uint32 need = 32u - nless;
        for (uint32 r=0; r<need; r++){
            u64 lmin = ~0ull;
            for (uint32 s=l; s<cb; s+=64){ u64 kk = cand[s]; if (kk < lmin) lmin = kk; }
            #pragma unroll
            for (int off=32; off>=1; off>>=1){
                u64 o = shfl_xor_u64(lmin, off);
                if (o < lmin) lmin = o;
            }
            for (uint32 s=l; s<cb; s+=64){ if (cand[s]==lmin) cand[s] = ~0ull; }
            if (l==0) out_keys[nless + r] = lmin;
        }
        u64 key = (l < 32) ? out_keys[l] : ~0ull;
        #pragma unroll
        for (uint32 k=2; k<=64; k<<=1){
            bool dir = ((l & k)==0);
            #pragma unroll
            for (uint32 j=k>>1; j>=1; j>>=1){
                u64 o = shfl_xor_u64(key, j);
                bool lower = ((l & j)==0);
                u64 mn = (key < o) ? key : o;
                u64 mx = (key < o) ? o : key;
                key = (lower == dir) ? mn : mx;
            }
        }
        if (l < 32) idxg[(long)bs*K_ + l] = (int)(key & 0xFFFFFFFFull);
    }
}

// ---------------- build features: A[col][c], col=(b*S+s)*K+k ----------------
__global__ __launch_bounds__(256) void build_kernel(const float* __restrict__ xT, const int* __restrict__ fps,
                                                    const int* __restrict__ idxg, ushort_t* __restrict__ A){
    long col = (long)blockIdx.x*256 + threadIdx.x;
    long bs  = col >> 5;
    int  b   = (int)(bs >> 10);
    int  n   = idxg[col];
    int  cn  = fps[bs];
    const float4* pr = (const float4*)(xT + ((long)b*N_ + n )*64);
    const float4* cr = (const float4*)(xT + ((long)b*N_ + cn)*64);
    ushort_t* op = A + col*C_;
    #pragma unroll
    for (int j=0;j<16;j++){
        float4 p = pr[j], c = cr[j];
        uint2 d, e;
        d.x = (((uint32)f2bf(p.y-c.y))<<16) | f2bf(p.x-c.x);
        d.y = (((uint32)f2bf(p.w-c.w))<<16) | f2bf(p.z-c.z);
        e.x = (((uint32)f2bf(c.y))<<16) | f2bf(c.x);
        e.y = (((uint32)f2bf(c.w))<<16) | f2bf(c.z);
        *(uint2*)(op + j*4)      = d;
        *(uint2*)(op + 64 + j*4) = e;
    }
}

// ---------------- convert all 10 weight matrices f32 -> bf16 ----------------
__global__ __launch_bounds__(256) void wcvt_kernel(const float* __restrict__ pcw, const float* __restrict__ pfw,
                                                   const float* __restrict__ qcw, const float* __restrict__ qfw,
                                                   ushort_t* __restrict__ Wb){
    int i = blockIdx.x*256 + threadIdx.x;   // 0 .. 163839
    int mat = i >> 14;
    int r = i & 16383;
    float v;
    if (mat < 4)      v = pcw[i];
    else if (mat == 4) v = pfw[r];
    else if (mat < 9)  v = qcw[i - 5*16384];
    else               v = qfw[r];
    Wb[i] = f2bf(v);
}

// ---------------- MFMA conv ----------------
// MODE: 0 RAW (B=in1) | 1 PRE (B=gelu(bn(in1))) | 2 RESID (B=gelu(bn(in1)+in2), aux-store B)
// PROLOG: 0 scsh from gmem | 1 reduce pbprev[256][nb] in-block (ext2, nb=64)
// Partials out: pb[tid*nb + blockIdx] (rows 0..127 sum, 128..255 sumsq)
template<int MODE, int PROLOG>
__global__ __launch_bounds__(256) void conv_mfma(const ushort_t* in1, const ushort_t* in2, ushort_t* aux,
                                                 ushort_t* out, const ushort_t* __restrict__ Wb,
                                                 const float* __restrict__ scsh_g, const float* __restrict__ pbprev,
                                                 const float* __restrict__ g, const float* __restrict__ bb,
                                                 float* __restrict__ pb, int nb, float inv_cnt){
    __shared__ float ss[256];
    __shared__ float sL[4][64], qL[4][64];
    int tid = threadIdx.x;
    int w = tid >> 6, l = tid & 63;
    int l15 = l & 15, l4 = l >> 4;

    if (MODE > 0){
        if (PROLOG){
            if (tid < 128){
                const float4* ps = (const float4*)(pbprev + tid*64);
                const float4* pq = (const float4*)(pbprev + (128+tid)*64);
                float s=0.f, q=0.f;
                #pragma unroll
                for (int i=0;i<16;i++){ float4 a=ps[i]; s += (a.x+a.y)+(a.z+a.w); }
                #pragma unroll
                for (int i=0;i<16;i++){ float4 a=pq[i]; q += (a.x+a.y)+(a.z+a.w); }
                float mean = s*inv_cnt, var = q*inv_cnt - mean*mean;
                float sc = g[tid]*rsqrtf(var+EPS_);
                ss[tid*2]   = sc;
                ss[tid*2+1] = bb[tid] - mean*sc;
            }
        } else {
            ss[tid] = scsh_g[tid];
        }
        __syncthreads();
    }

    int oc0 = (w & 1) << 6;
    long col0 = ((long)blockIdx.x << 7) + ((long)(w >> 1) << 6);

    f32x4 acc[4][4] = {};
    s16x8 keep[2][4];
    #pragma unroll
    for (int ks=0; ks<4; ks++){
        int kl = ks*32 + l4*8;
        s16x8 af[4];
        #pragma unroll
        for (int m=0;m<4;m++)
            af[m] = *(const s16x8*)(Wb + (oc0 + m*16 + l15)*C_ + kl);
        float sc[8], sh[8];
        if (MODE > 0){
            const float4* sp = (const float4*)(&ss[kl*2]);
            float4 s0 = sp[0], s1 = sp[1], s2 = sp[2], s3 = sp[3];
            sc[0]=s0.x; sh[0]=s0.y; sc[1]=s0.z; sh[1]=s0.w;
            sc[2]=s1.x; sh[2]=s1.y; sc[3]=s1.z; sh[3]=s1.w;
            sc[4]=s2.x; sh[4]=s2.y; sc[5]=s2.z; sh[5]=s2.w;
            sc[6]=s3.x; sh[6]=s3.y; sc[7]=s3.z; sh[7]=s3.w;
        }
        s16x8 bfr[4];
        #pragma unroll
        for (int n=0;n<4;n++){
            long cbase = (col0 + n*16 + l15)*C_ + kl;
            s16x8 v = *(const s16x8*)(in1 + cbase);
            if (MODE == 1){
                #pragma unroll
                for (int e=0;e<8;e++){
                    float f = gelu_f(fmaf(bf2f((ushort_t)v[e]), sc[e], sh[e]));
                    v[e] = (short)f2bf(f);
                }
            } else if (MODE == 2){
                s16x8 a = *(const s16x8*)(in2 + cbase);
                #pragma unroll
                for (int e=0;e<8;e++){
                    float f = gelu_f(fmaf(bf2f((ushort_t)v[e]), sc[e], sh[e]) + bf2f((ushort_t)a[e]));
                    v[e] = (short)f2bf(f);
                }
            }
            bfr[n] = v;
        }
        if (MODE == 2){
            if ((ks>>1) == (w&1)){                // this wave retains ks pair {2*(w&1), +1}
                #pragma unroll
                for (int n=0;n<4;n++) keep[ks&1][n] = bfr[n];
            }
        }
        #pragma unroll
        for (int m=0;m<4;m++)
            #pragma unroll
            for (int n=0;n<4;n++)
                acc[m][n] = __builtin_amdgcn_mfma_f32_16x16x32_bf16(af[m], bfr[n], acc[m][n], 0, 0, 0);
    }

    __syncthreads();   // in-place safety: all input loads complete before any store

    if (MODE == 2){
        #pragma unroll
        for (int kk=0;kk<2;kk++){
            int ks = ((w&1)<<1) + kk;
            int kl = ks*32 + l4*8;
            #pragma unroll
            for (int n=0;n<4;n++)
                *(s16x8*)(aux + (col0 + n*16 + l15)*C_ + kl) = keep[kk][n];
        }
    }

    #pragma unroll
    for (int n=0;n<4;n++){
        long cadr = (col0 + n*16 + l15)*C_;
        #pragma unroll
        for (int m=0;m<4;m++){
            f32x4 a = acc[m][n];
            uint2 st;
            st.x = (((uint32)f2bf(a[1]))<<16) | f2bf(a[0]);
            st.y = (((uint32)f2bf(a[3]))<<16) | f2bf(a[2]);
            *(uint2*)(out + cadr + oc0 + m*16 + l4*4) = st;
        }
    }

    // BN-stat partials over this block's 128 cols
    #pragma unroll
    for (int m=0;m<4;m++){
        #pragma unroll
        for (int r=0;r<4;r++){
            float a0=acc[m][0][r], a1=acc[m][1][r], a2=acc[m][2][r], a3=acc[m][3][r];
            float s = (a0+a1)+(a2+a3);
            float q = (a0*a0+a1*a1)+(a2*a2+a3*a3);
            #pragma unroll
            for (int off=1; off<16; off<<=1){
                s += __shfl_xor(s, off, 64);
                q += __shfl_xor(q, off, 64);
            }
            if (l15 == 0){
                sL[w][m*16 + l4*4 + r] = s;
                qL[w][m*16 + l4*4 + r] = q;
            }
        }
    }
    __syncthreads();
    if (tid < 128){
        int half = tid >> 6, rel = tid & 63;
        float s = sL[half][rel] + sL[half+2][rel];
        float q = qL[half][rel] + qL[half+2][rel];
        pb[(long)tid*nb + blockIdx.x]       = s;
        pb[(long)(128+tid)*nb + blockIdx.x] = q;
    }
}

// ---------------- reduce partials[256][nb] -> (scale, shift) ----------------
__global__ __launch_bounds__(256) void reduce_fin_kernel(const float* __restrict__ pb, float* __restrict__ scsh,
                                                         const float* __restrict__ g, const float* __restrict__ bb,
                                                         float inv_cnt, int nb){
    int oc = blockIdx.x;    // 128 blocks
    float s=0.f, q=0.f;
    for (int b=threadIdx.x; b<nb; b+=256){
        s += pb[(long)oc*nb + b];
        q += pb[(long)(128+oc)*nb + b];
    }
    __shared__ float ls[256], lq[256];
    ls[threadIdx.x]=s; lq[threadIdx.x]=q;
    __syncthreads();
    #pragma unroll
    for (int st_=128; st_>0; st_>>=1){
        if (threadIdx.x < st_){ ls[threadIdx.x]+=ls[threadIdx.x+st_]; lq[threadIdx.x]+=lq[threadIdx.x+st_]; }
        __syncthreads();
    }
    if (threadIdx.x==0){
        float mean = ls[0]*inv_cnt;
        float var  = lq[0]*inv_cnt - mean*mean;
        float sc   = g[oc]*rsqrtf(var + EPS_);
        scsh[oc*2+0] = sc;
        scsh[oc*2+1] = bb[oc] - mean*sc;
    }
}

// ---------------- pool with fused resid: A2[bs][c] = max_k gelu(bn(T)+X) ----------------
__global__ __launch_bounds__(256) void pool_kernel(const ushort_t* __restrict__ T, const ushort_t* __restrict__ X,
                                                   const float* __restrict__ scsh, ushort_t* __restrict__ A2){
    long p  = (long)blockIdx.x*256 + threadIdx.x;    // 8192*64
    long bs = p >> 6;
    int  c0 = ((int)p & 63)*2;
    float sc0=scsh[c0*2], sh0=scsh[c0*2+1], sc1=scsh[c0*2+2], sh1=scsh[c0*2+3];
    const ushort_t* tb = T + (bs*K_)*(long)C_ + c0;
    const ushort_t* xv = X + (bs*K_)*(long)C_ + c0;
    float m0 = -1e30f, m1 = -1e30f;
    #pragma unroll 4
    for (int k=0;k<K_;k++){
        uint32 tv = *(const uint32*)(tb + (long)k*C_);
        uint32 av = *(const uint32*)(xv + (long)k*C_);
        float v0 = gelu_f(fmaf(bf2f((ushort_t)(tv & 0xFFFFu)), sc0, sh0) + bf2f((ushort_t)(av & 0xFFFFu)));
        float v1 = gelu_f(fmaf(bf2f((ushort_t)(tv >> 16)),     sc1, sh1) + bf2f((ushort_t)(av >> 16)));
        m0 = fmaxf(m0, v0);
        m1 = fmaxf(m1, v1);
    }
    uint32 o = (((uint32)f2bf(m1))<<16) | f2bf(m0);
    *(uint32*)(A2 + bs*C_ + c0) = o;
}

// ---------------- final output: y[b][c][s] = gelu(bn(T)+X) transposed, f32 ----------------
__global__ __launch_bounds__(256) void out_kernel(const ushort_t* __restrict__ T, const ushort_t* __restrict__ X,
                                                  const float* __restrict__ scsh, float* __restrict__ y){
    long o = (long)blockIdx.x*256 + threadIdx.x;     // B*C*S
    int s = (int)(o & (S_-1));
    int c = (int)((o >> 10) & (C_-1));
    int b = (int)(o >> 17);
    long ad = ((long)(b*S_ + s))*C_ + c;
    float v = gelu_f(fmaf(bf2f(T[ad]), scsh[c*2], scsh[c*2+1]) + bf2f(X[ad]));
    y[o] = v;
}

extern "C" void kernel_launch(void* const* d_in, const int* in_sizes, int n_in,
                              void* d_out, int out_size, void* d_ws, size_t ws_size,
                              hipStream_t stream){
    const float* xyz        = (const float*)d_in[0];
    const float* x          = (const float*)d_in[1];
    const int*   fps        = (const int*)d_in[2];
    const float* pre_bn_g   = (const float*)d_in[4];
    const float* pre_bn_b   = (const float*)d_in[5];
    const float* pre_ffn_g  = (const float*)d_in[7];
    const float* pre_ffn_b  = (const float*)d_in[8];
    const float* pos_bn_g   = (const float*)d_in[10];
    const float* pos_bn_b   = (const float*)d_in[11];
    const float* pos_ffn_g  = (const float*)d_in[13];
    const float* pos_ffn_b  = (const float*)d_in[14];

    float* out_xyz = (float*)d_out;
    float* out_y   = (float*)d_out + (long)B_*S_*3;

    // ws layout (bytes):
    //   0        scsh   (6*256 floats used; reserve 10240)
    //   10240    pb2a (64KB) ; 75776 pb2b (64KB)
    //   141312   Wb (327680) -> 468992
    //   468992   idx (1MB, knn/build) THEN pb (2MB, ext1 convs) -> 2566144
    //   2566144  xT (8MB, until build) THEN A2(2MB)@2566144 + C2(2MB)@4663296
    //   10954752 A1 (64MiB = 67108864) -> 78063616
    //   78063616 Cb (64MiB) -> 145172480
    char* ws = (char*)d_ws;
    float*    scsh  = (float*)(ws + 0);
    float*    pb2a  = (float*)(ws + 10240);
    float*    pb2b  = (float*)(ws + 75776);
    ushort_t* Wb    = (ushort_t*)(ws + 141312);
    int*      idx   = (int*)(ws + 468992);
    float*    pb    = (float*)(ws + 468992);
    float*    xT    = (float*)(ws + 2566144);
    ushort_t* A2    = (ushort_t*)(ws + 2566144);
    ushort_t* C2    = (ushort_t*)(ws + 4663296);
    ushort_t* A1    = (ushort_t*)(ws + 10954752);
    ushort_t* Cb    = (ushort_t*)(ws + 78063616);
    (void)in_sizes; (void)n_in; (void)out_size; (void)ws_size;

    const float inv1 = 1.0f/(float)NCOL1, inv2 = 1.0f/(float)NCOL2;
    const ushort_t* Wp = Wb;            // pre weights (5 mats)
    const ushort_t* Wq = Wb + 5*C_*C_;  // pos weights (5 mats)

    wcvt_kernel<<<640,256,0,stream>>>((const float*)d_in[3], (const float*)d_in[6],
                                      (const float*)d_in[9], (const float*)d_in[12], Wb);
    transpose_kernel<<<B_*(N_/64),256,0,stream>>>(x, xT);
    knn_kernel<<<B_*S_,256,0,stream>>>(xyz, fps, idx, out_xyz);
    build_kernel<<<NCOL1/256,256,0,stream>>>(xT, fps, idx, A1);

    // -------- extraction 1 (ncol = 262144, nb = 2048) --------
    {
        int nb = NCOL1/128;
        const float* G[5]  = {pre_bn_g, pre_bn_g+C_, pre_bn_g+2*C_, pre_bn_g+3*C_, pre_ffn_g};
        const float* Bv[5] = {pre_bn_b, pre_bn_b+C_, pre_bn_b+2*C_, pre_bn_b+3*C_, pre_ffn_b};
        conv_mfma<0,0><<<nb,256,0,stream>>>(A1, nullptr, nullptr, Cb, Wp+0*C_*C_, nullptr, nullptr, nullptr, nullptr, pb, nb, inv1);
        reduce_fin_kernel<<<128,256,0,stream>>>(pb, scsh+0*256, G[0], Bv[0], inv1, nb);
        conv_mfma<1,0><<<nb,256,0,stream>>>(Cb, nullptr, nullptr, Cb, Wp+1*C_*C_, scsh+0*256, nullptr, nullptr, nullptr, pb, nb, inv1);
        reduce_fin_kernel<<<128,256,0,stream>>>(pb, scsh+1*256, G[1], Bv[1], inv1, nb);
        conv_mfma<2,0><<<nb,256,0,stream>>>(Cb, A1, A1, Cb, Wp+2*C_*C_, scsh+1*256, nullptr, nullptr, nullptr, pb, nb, inv1);
        reduce_fin_kernel<<<128,256,0,stream>>>(pb, scsh+2*256, G[2], Bv[2], inv1, nb);
        conv_mfma<1,0><<<nb,256,0,stream>>>(Cb, nullptr, nullptr, Cb, Wp+3*C_*C_, scsh+2*256, nullptr, nullptr, nullptr, pb, nb, inv1);
        reduce_fin_kernel<<<128,256,0,stream>>>(pb, scsh+3*256, G[3], Bv[3], inv1, nb);
        conv_mfma<2,0><<<nb,256,0,stream>>>(Cb, A1, A1, Cb, Wp+4*C_*C_, scsh+3*256, nullptr, nullptr, nullptr, pb, nb, inv1);
        reduce_fin_kernel<<<128,256,0,stream>>>(pb, scsh+4*256, G[4], Bv[4], inv1, nb);
        pool_kernel<<<(NCOL2*64)/256,256,0,stream>>>(Cb, A1, scsh+4*256, A2);
    }

    // -------- extraction 2 (ncol = 8192, nb = 64) --------
    {
        int nb = NCOL2/128;
        const float* G[5]  = {pos_bn_g, pos_bn_g+C_, pos_bn_g+2*C_, pos_bn_g+3*C_, pos_ffn_g};
        const float* Bv[5] = {pos_bn_b, pos_bn_b+C_, pos_bn_b+2*C_, pos_bn_b+3*C_, pos_ffn_b};
        conv_mfma<0,1><<<nb,256,0,stream>>>(A2, nullptr, nullptr, C2, Wq+0*C_*C_, nullptr, nullptr, nullptr, nullptr, pb2a, nb, inv2);
        conv_mfma<1,1><<<nb,256,0,stream>>>(C2, nullptr, nullptr, C2, Wq+1*C_*C_, nullptr, pb2a, G[0], Bv[0], pb2b, nb, inv2);
        conv_mfma<2,1><<<nb,256,0,stream>>>(C2, A2, A2, C2, Wq+2*C_*C_, nullptr, pb2b, G[1], Bv[1], pb2a, nb, inv2);
        conv_mfma<1,1><<<nb,256,0,stream>>>(C2, nullptr, nullptr, C2, Wq+3*C_*C_, nullptr, pb2a, G[2], Bv[2], pb2b, nb, inv2);
        conv_mfma<2,1><<<nb,256,0,stream>>>(C2, A2, A2, C2, Wq+4*C_*C_, nullptr, pb2b, G[3], Bv[3], pb2a, nb, inv2);
        reduce_fin_kernel<<<128,256,0,stream>>>(pb2a, scsh+5*256, G[4], Bv[4], inv2, nb);
        out_kernel<<<(B_*C_*S_)/256,256,0,stream>>>(C2, A2, scsh+5*256, out_y);
    }
}

// Round 6
// 658.019 us; speedup vs baseline: 6.6765x; 1.0576x over previous
//
#include <hip/hip_runtime.h>
#include <math.h>

typedef unsigned short ushort_t;
typedef unsigned long long u64;
typedef unsigned int uint32;

#define B_ 8
#define N_ 4096
#define S_ 1024
#define K_ 32
#define C_ 128
#define NCOL1 (B_*S_*K_)   // 262144
#define NCOL2 (B_*S_)      // 8192
#define EPS_ 1e-5f

typedef ushort_t us8 __attribute__((ext_vector_type(8)));
typedef short s16x8 __attribute__((ext_vector_type(8)));
typedef float f32x4 __attribute__((ext_vector_type(4)));

__device__ __forceinline__ float bf2f(ushort_t u){ return __uint_as_float(((uint32)u)<<16); }
__device__ __forceinline__ ushort_t f2bf(float f){
    uint32 x = __float_as_uint(f);
    return (ushort_t)((x + 0x7FFFu + ((x>>16)&1u)) >> 16);
}
// gelu with A&S 7.1.26 erf: |err| <= 1.5e-7, branchless, ~14 VALU ops
__device__ __forceinline__ float gelu_f(float v){
    float az = fabsf(v)*0.70710678118654752f;
    float t  = __builtin_amdgcn_rcpf(fmaf(0.3275911f, az, 1.0f));
    float p  = fmaf(fmaf(fmaf(fmaf(1.061405429f, t, -1.453152027f), t, 1.421413741f), t,
                   -0.284496736f), t, 0.254829592f)*t;
    float e  = __expf(-az*az);
    float er = fmaf(-p, e, 1.0f);                    // erf(|z|)
    float s  = (v < 0.0f) ? -er : er;
    return 0.5f*v*(1.0f+s);
}
__device__ __forceinline__ u64 shfl_xor_u64(u64 v, int m){
    int lo = __shfl_xor((int)(v & 0xFFFFFFFFull), m, 64);
    int hi = __shfl_xor((int)(v >> 32), m, 64);
    return (((u64)(uint32)hi) << 32) | (uint32)lo;
}

// ---------------- transpose x (B,64,N) -> xT (B,N,64) ----------------
__global__ __launch_bounds__(256) void transpose_kernel(const float* __restrict__ x, float* __restrict__ xT){
    __shared__ float t[64][65];
    int b  = blockIdx.x >> 6;
    int n0 = (blockIdx.x & 63) * 64;
    int tx = threadIdx.x & 63, ty = threadIdx.x >> 6;
    #pragma unroll
    for (int i=0;i<16;i++){
        int c = i*4 + ty;
        t[c][tx] = x[((long)(b*64 + c))*N_ + n0 + tx];
    }
    __syncthreads();
    #pragma unroll
    for (int i=0;i<16;i++){
        int n = i*4 + ty;
        xT[((long)(b*N_ + n0 + n))*64 + tx] = t[tx][n];
    }
}

// ---------------- KNN: 2-level radix select (1024/4096 bins), exact, low-LDS ----------------
__global__ __launch_bounds__(256) void knn_kernel(const float* __restrict__ xyz, const int* __restrict__ fps,
                                                  int* __restrict__ idxg, float* __restrict__ newxyz){
    __shared__ uint32 hist[4096];      // 16 KB (pass1 uses first 1024)
    __shared__ u64    cand[1024];      // 8 KB
    __shared__ u64    out_keys[64];
    __shared__ uint32 csum[256];
    __shared__ uint32 wtot[4];
    __shared__ uint32 shv[8];          // 0:b1 1:cl1 2:b2 3:cl2 4:sel 5:cand
    __shared__ u64    wred[4];
    __shared__ u64    winner;

    int tid = threadIdx.x;
    int wv = tid >> 6, l = tid & 63;
    int bs = blockIdx.x;
    int b  = bs >> 10;
    int qi = fps[bs];
    const float* qb = xyz + ((long)b*N_ + qi)*3;
    float qx = qb[0], qy = qb[1], qz = qb[2];
    if (tid < 3) newxyz[(long)bs*3 + tid] = qb[tid];
    const float* xb = xyz + (long)b*N_*3;

    for (int i=tid;i<1024;i+=256) hist[i]=0;
    if (tid < 8) shv[tid]=0;
    __syncthreads();

    // pass 1: distances (regs) + level-1 histogram (bits 30..21, 1024 bins)
    uint32 dbits[16];
    #pragma unroll
    for (int i=0;i<16;i++){
        int n = i*256 + tid;
        float dx = xb[n*3+0]-qx, dy = xb[n*3+1]-qy, dz = xb[n*3+2]-qz;
        float d = dx*dx + dy*dy + dz*dz;
        dbits[i] = __float_as_uint(d);
        atomicAdd(&hist[dbits[i]>>21], 1u);
    }
    __syncthreads();

    // scan level 1 (4 bins/thread), find bin of rank 31
    {
        uint32 h4[4]; uint32 csumv=0;
        #pragma unroll
        for (int i=0;i<4;i++){ h4[i]=hist[tid*4+i]; csumv+=h4[i]; }
        uint32 sc = csumv;
        #pragma unroll
        for (int off=1; off<64; off<<=1){ uint32 o=__shfl_up(sc,off,64); if (l>=off) sc+=o; }
        if (l==63) wtot[wv]=sc;
        csum[tid]=sc;
        __syncthreads();
        uint32 base=0;
        for (int w2=0; w2<wv; w2++) base += wtot[w2];
        uint32 cum = base + csum[tid] - csumv;
        #pragma unroll
        for (int i=0;i<4;i++){
            if (cum <= 31u && 31u < cum + h4[i]){ shv[0]=(uint32)(tid*4+i); shv[1]=cum; }
            cum += h4[i];
        }
    }
    __syncthreads();
    uint32 b1 = shv[0], cl1 = shv[1];

    // pass 2: level-2 histogram (bits 20..9, 4096 bins) within bin b1
    for (int i=tid;i<4096;i+=256) hist[i]=0;
    __syncthreads();
    #pragma unroll
    for (int i=0;i<16;i++){
        uint32 u = dbits[i];
        if ((u>>21)==b1) atomicAdd(&hist[(u>>9)&0xFFFu], 1u);
    }
    __syncthreads();

    uint32 r2 = 31u - cl1;
    {
        uint32 h[16]; uint32 csumv=0;
        #pragma unroll
        for (int i=0;i<16;i++){ h[i]=hist[tid*16+i]; csumv += h[i]; }
        uint32 sc = csumv;
        #pragma unroll
        for (int off=1; off<64; off<<=1){ uint32 o=__shfl_up(sc,off,64); if (l>=off) sc+=o; }
        if (l==63) wtot[wv]=sc;
        csum[tid]=sc;
        __syncthreads();
        uint32 base=0;
        for (int w2=0; w2<wv; w2++) base += wtot[w2];
        uint32 cum = base + csum[tid] - csumv;
        #pragma unroll
        for (int i=0;i<16;i++){
            if (cum <= r2 && r2 < cum + h[i]){ shv[2]=(uint32)(tid*16+i); shv[3]=cum; }
            cum += h[i];
        }
    }
    __syncthreads();
    uint32 b2 = shv[2], cl2 = shv[3];
    uint32 nless = cl1 + cl2;

    // pass 3: collect sure-winners + boundary candidates (guarded)
    #pragma unroll
    for (int i=0;i<16;i++){
        uint32 u = dbits[i];
        int n = i*256 + tid;
        uint32 bb1 = u >> 21;
        if (bb1 > b1) continue;
        u64 key = (((u64)u)<<32) | (uint32)n;
        if (bb1 < b1){
            uint32 p = atomicAdd(&shv[4],1u); out_keys[p] = key;
        } else {
            uint32 bb2 = (u>>9)&0xFFFu;
            if (bb2 < b2){ uint32 p = atomicAdd(&shv[4],1u); out_keys[p] = key; }
            else if (bb2 == b2){ uint32 p = atomicAdd(&shv[5],1u); if (p < 1024u) cand[p] = key; }
        }
    }
    __syncthreads();

    if (shv[5] > 1024u){
        // exact fallback (massive tie class): serial 32-round block argmin
        uint32 alive = 0xFFFFu;
        for (int r=0;r<K_;r++){
            u64 lmin = ~0ull;
            #pragma unroll
            for (int i=0;i<16;i++){
                u64 k = (((u64)dbits[i])<<32) | (uint32)(i*256+tid);
                if (((alive>>i)&1u) && k < lmin) lmin = k;
            }
            #pragma unroll
            for (int off=32; off>=1; off>>=1){
                u64 o = shfl_xor_u64(lmin, off);
                if (o < lmin) lmin = o;
            }
            if (l == 0) wred[wv] = lmin;
            __syncthreads();
            if (tid == 0){
                u64 m = wred[0];
                if (wred[1]<m) m=wred[1];
                if (wred[2]<m) m=wred[2];
                if (wred[3]<m) m=wred[3];
                winner = m;
                idxg[(long)bs*K_ + r] = (int)(m & 0xFFFFFFFFull);
            }
            __syncthreads();
            u64 w = winner;
            #pragma unroll
            for (int i=0;i<16;i++){
                u64 k = (((u64)dbits[i])<<32) | (uint32)(i*256+tid);
                if (k == w) alive &= ~(1u<<i);
            }
        }
    } else if (wv == 0){
        uint32 cb   = shv[5];
        uint32 need = 32u - nless;
        for (uint32 r=0; r<need; r++){
            u64 lmin = ~0ull;
            for (uint32 s=l; s<cb; s+=64){ u64 kk = cand[s]; if (kk < lmin) lmin = kk; }
            #pragma unroll
            for (int off=32; off>=1; off>>=1){
                u64 o = shfl_xor_u64(lmin, off);
                if (o < lmin) lmin = o;
            }
            for (uint32 s=l; s<cb; s+=64){ if (cand[s]==lmin) cand[s] = ~0ull; }
            if (l==0) out_keys[nless + r] = lmin;
        }
        u64 key = (l < 32) ? out_keys[l] : ~0ull;
        #pragma unroll
        for (uint32 k=2; k<=64; k<<=1){
            bool dir = ((l & k)==0);
            #pragma unroll
            for (uint32 j=k>>1; j>=1; j>>=1){
                u64 o = shfl_xor_u64(key, j);
                bool lower = ((l & j)==0);
                u64 mn = (key < o) ? key : o;
                u64 mx = (key < o) ? o : key;
                key = (lower == dir) ? mn : mx;
            }
        }
        if (l < 32) idxg[(long)bs*K_ + l] = (int)(key & 0xFFFFFFFFull);
    }
}

// ---------------- build features: A[col][c], col=(b*S+s)*K+k ----------------
__global__ __launch_bounds__(256) void build_kernel(const float* __restrict__ xT, const int* __restrict__ fps,
                                                    const int* __restrict__ idxg, ushort_t* __restrict__ A){
    long col = (long)blockIdx.x*256 + threadIdx.x;
    long bs  = col >> 5;
    int  b   = (int)(bs >> 10);
    int  n   = idxg[col];
    int  cn  = fps[bs];
    const float4* pr = (const float4*)(xT + ((long)b*N_ + n )*64);
    const float4* cr = (const float4*)(xT + ((long)b*N_ + cn)*64);
    ushort_t* op = A + col*C_;
    #pragma unroll
    for (int j=0;j<16;j++){
        float4 p = pr[j], c = cr[j];
        uint2 d, e;
        d.x = (((uint32)f2bf(p.y-c.y))<<16) | f2bf(p.x-c.x);
        d.y = (((uint32)f2bf(p.w-c.w))<<16) | f2bf(p.z-c.z);
        e.x = (((uint32)f2bf(c.y))<<16) | f2bf(c.x);
        e.y = (((uint32)f2bf(c.w))<<16) | f2bf(c.z);
        *(uint2*)(op + j*4)      = d;
        *(uint2*)(op + 64 + j*4) = e;
    }
}

// ---------------- convert all 10 weight matrices f32 -> bf16 ----------------
__global__ __launch_bounds__(256) void wcvt_kernel(const float* __restrict__ pcw, const float* __restrict__ pfw,
                                                   const float* __restrict__ qcw, const float* __restrict__ qfw,
                                                   ushort_t* __restrict__ Wb){
    int i = blockIdx.x*256 + threadIdx.x;   // 0 .. 163839
    int mat = i >> 14;
    int r = i & 16383;
    float v;
    if (mat < 4)      v = pcw[i];
    else if (mat == 4) v = pfw[r];
    else if (mat < 9)  v = qcw[i - 5*16384];
    else               v = qfw[r];
    Wb[i] = f2bf(v);
}

// ---------------- MFMA conv, wave-private 32-col tiles ----------------
// Each wave owns 32 cols x all 128 oc -> in-place out/aux writes are hazard-free by
// dataflow (no mid-kernel barrier). All B/resid loads issued upfront for deep MLP.
// MODE: 0 RAW (B=in1) | 1 PRE (B=gelu(bn(in1))) | 2 RESID (B=gelu(bn(in1)+in2), aux-store B)
// PROLOG: 0 scsh from gmem | 1 reduce pbprev[256][nb] in-block (ext2, nb=64)
// Partials out: pb[tid*nb + blockIdx] (rows 0..127 sum, 128..255 sumsq)
template<int MODE, int PROLOG>
__global__ __launch_bounds__(256) void conv_mfma(const ushort_t* in1, const ushort_t* in2, ushort_t* aux,
                                                 ushort_t* out, const ushort_t* __restrict__ Wb,
                                                 const float* __restrict__ scsh_g, const float* __restrict__ pbprev,
                                                 const float* __restrict__ g, const float* __restrict__ bb,
                                                 float* __restrict__ pb, int nb, float inv_cnt){
    __shared__ float ss[256];
    __shared__ float sL[4][128], qL[4][128];
    int tid = threadIdx.x;
    int w = tid >> 6, l = tid & 63;
    int l15 = l & 15, l4 = l >> 4;

    if (MODE > 0){
        if (PROLOG){
            if (tid < 128){
                const float4* ps = (const float4*)(pbprev + tid*64);
                const float4* pq = (const float4*)(pbprev + (128+tid)*64);
                float s=0.f, q=0.f;
                #pragma unroll
                for (int i=0;i<16;i++){ float4 a=ps[i]; s += (a.x+a.y)+(a.z+a.w); }
                #pragma unroll
                for (int i=0;i<16;i++){ float4 a=pq[i]; q += (a.x+a.y)+(a.z+a.w); }
                float mean = s*inv_cnt, var = q*inv_cnt - mean*mean;
                float sc = g[tid]*rsqrtf(var+EPS_);
                ss[tid*2]   = sc;
                ss[tid*2+1] = bb[tid] - mean*sc;
            }
        } else {
            ss[tid] = scsh_g[tid];
        }
        __syncthreads();
    }

    long col0 = ((long)blockIdx.x << 7) + ((long)w << 5);   // wave-private 32 cols

    // stage all activation loads upfront (8 x 16B in1, + 8 x 16B in2 for MODE 2)
    s16x8 bfr[8];
    #pragma unroll
    for (int t=0;t<8;t++){
        int n = t>>2, ks = t&3;
        bfr[t] = *(const s16x8*)(in1 + (col0 + n*16 + l15)*C_ + ks*32 + l4*8);
    }
    s16x8 a2[8];
    if (MODE == 2){
        #pragma unroll
        for (int t=0;t<8;t++){
            int n = t>>2, ks = t&3;
            a2[t] = *(const s16x8*)(in2 + (col0 + n*16 + l15)*C_ + ks*32 + l4*8);
        }
    }

    f32x4 acc[8][2] = {};                            // [mblk=oc][nblk=col]
    #pragma unroll
    for (int ks=0; ks<4; ks++){
        int kl = ks*32 + l4*8;
        s16x8 af[8];
        #pragma unroll
        for (int m=0;m<8;m++)
            af[m] = *(const s16x8*)(Wb + (m*16 + l15)*C_ + kl);
        if (MODE > 0){
            float sc[8], sh[8];
            const float4* sp = (const float4*)(&ss[kl*2]);
            float4 s0 = sp[0], s1 = sp[1], s2 = sp[2], s3 = sp[3];
            sc[0]=s0.x; sh[0]=s0.y; sc[1]=s0.z; sh[1]=s0.w;
            sc[2]=s1.x; sh[2]=s1.y; sc[3]=s1.z; sh[3]=s1.w;
            sc[4]=s2.x; sh[4]=s2.y; sc[5]=s2.z; sh[5]=s2.w;
            sc[6]=s3.x; sh[6]=s3.y; sc[7]=s3.z; sh[7]=s3.w;
            #pragma unroll
            for (int n=0;n<2;n++){
                s16x8 v = bfr[n*4+ks];
                if (MODE == 1){
                    #pragma unroll
                    for (int e=0;e<8;e++){
                        float f = gelu_f(fmaf(bf2f((ushort_t)v[e]), sc[e], sh[e]));
                        v[e] = (short)f2bf(f);
                    }
                } else {
                    s16x8 a = a2[n*4+ks];
                    #pragma unroll
                    for (int e=0;e<8;e++){
                        float f = gelu_f(fmaf(bf2f((ushort_t)v[e]), sc[e], sh[e]) + bf2f((ushort_t)a[e]));
                        v[e] = (short)f2bf(f);
                    }
                }
                bfr[n*4+ks] = v;
                if (MODE == 2)
                    *(s16x8*)(aux + (col0 + n*16 + l15)*C_ + kl) = v;   // wave-private col: safe
            }
        }
        #pragma unroll
        for (int m=0;m<8;m++)
            #pragma unroll
            for (int n=0;n<2;n++)
                acc[m][n] = __builtin_amdgcn_mfma_f32_16x16x32_bf16(af[m], bfr[n*4+ks], acc[m][n], 0, 0, 0);
    }

    // out stores (wave-private cols; dataflow-ordered after this wave's own loads)
    #pragma unroll
    for (int n=0;n<2;n++){
        long cadr = (col0 + n*16 + l15)*C_;
        #pragma unroll
        for (int m=0;m<8;m++){
            f32x4 a = acc[m][n];
            uint2 st;
            st.x = (((uint32)f2bf(a[1]))<<16) | f2bf(a[0]);
            st.y = (((uint32)f2bf(a[3]))<<16) | f2bf(a[2]);
            *(uint2*)(out + cadr + m*16 + l4*4) = st;
        }
    }

    // BN-stat partials over this block's 128 cols (reduce over l15 then waves)
    #pragma unroll
    for (int m=0;m<8;m++){
        #pragma unroll
        for (int r=0;r<4;r++){
            float a0=acc[m][0][r], a1=acc[m][1][r];
            float s = a0+a1;
            float q = a0*a0+a1*a1;
            #pragma unroll
            for (int off=1; off<16; off<<=1){
                s += __shfl_xor(s, off, 64);
                q += __shfl_xor(q, off, 64);
            }
            if (l15 == 0){
                sL[w][m*16 + l4*4 + r] = s;
                qL[w][m*16 + l4*4 + r] = q;
            }
        }
    }
    __syncthreads();
    if (tid < 128){
        float s = sL[0][tid] + sL[1][tid] + sL[2][tid] + sL[3][tid];
        float q = qL[0][tid] + qL[1][tid] + qL[2][tid] + qL[3][tid];
        pb[(long)tid*nb + blockIdx.x]       = s;
        pb[(long)(128+tid)*nb + blockIdx.x] = q;
    }
}

// ---------------- reduce partials[256][nb] -> (scale, shift) ----------------
__global__ __launch_bounds__(256) void reduce_fin_kernel(const float* __restrict__ pb, float* __restrict__ scsh,
                                                         const float* __restrict__ g, const float* __restrict__ bb,
                                                         float inv_cnt, int nb){
    int oc = blockIdx.x;    // 128 blocks
    float s=0.f, q=0.f;
    for (int b=threadIdx.x; b<nb; b+=256){
        s += pb[(long)oc*nb + b];
        q += pb[(long)(128+oc)*nb + b];
    }
    __shared__ float ls[256], lq[256];
    ls[threadIdx.x]=s; lq[threadIdx.x]=q;
    __syncthreads();
    #pragma unroll
    for (int st_=128; st_>0; st_>>=1){
        if (threadIdx.x < st_){ ls[threadIdx.x]+=ls[threadIdx.x+st_]; lq[threadIdx.x]+=lq[threadIdx.x+st_]; }
        __syncthreads();
    }
    if (threadIdx.x==0){
        float mean = ls[0]*inv_cnt;
        float var  = lq[0]*inv_cnt - mean*mean;
        float sc   = g[oc]*rsqrtf(var + EPS_);
        scsh[oc*2+0] = sc;
        scsh[oc*2+1] = bb[oc] - mean*sc;
    }
}

// ---------------- pool with fused resid: A2[bs][c] = max_k gelu(bn(T)+X) ----------------
__global__ __launch_bounds__(256) void pool_kernel(const ushort_t* __restrict__ T, const ushort_t* __restrict__ X,
                                                   const float* __restrict__ scsh, ushort_t* __restrict__ A2){
    long p  = (long)blockIdx.x*256 + threadIdx.x;    // 8192*64
    long bs = p >> 6;
    int  c0 = ((int)p & 63)*2;
    float sc0=scsh[c0*2], sh0=scsh[c0*2+1], sc1=scsh[c0*2+2], sh1=scsh[c0*2+3];
    const ushort_t* tb = T + (bs*K_)*(long)C_ + c0;
    const ushort_t* xv = X + (bs*K_)*(long)C_ + c0;
    float m0 = -1e30f, m1 = -1e30f;
    #pragma unroll 4
    for (int k=0;k<K_;k++){
        uint32 tv = *(const uint32*)(tb + (long)k*C_);
        uint32 av = *(const uint32*)(xv + (long)k*C_);
        float v0 = gelu_f(fmaf(bf2f((ushort_t)(tv & 0xFFFFu)), sc0, sh0) + bf2f((ushort_t)(av & 0xFFFFu)));
        float v1 = gelu_f(fmaf(bf2f((ushort_t)(tv >> 16)),     sc1, sh1) + bf2f((ushort_t)(av >> 16)));
        m0 = fmaxf(m0, v0);
        m1 = fmaxf(m1, v1);
    }
    uint32 o = (((uint32)f2bf(m1))<<16) | f2bf(m0);
    *(uint32*)(A2 + bs*C_ + c0) = o;
}

// ---------------- final output: y[b][c][s] = gelu(bn(T)+X) transposed, f32 ----------------
__global__ __launch_bounds__(256) void out_kernel(const ushort_t* __restrict__ T, const ushort_t* __restrict__ X,
                                                  const float* __restrict__ scsh, float* __restrict__ y){
    long o = (long)blockIdx.x*256 + threadIdx.x;     // B*C*S
    int s = (int)(o & (S_-1));
    int c = (int)((o >> 10) & (C_-1));
    int b = (int)(o >> 17);
    long ad = ((long)(b*S_ + s))*C_ + c;
    float v = gelu_f(fmaf(bf2f(T[ad]), scsh[c*2], scsh[c*2+1]) + bf2f(X[ad]));
    y[o] = v;
}

extern "C" void kernel_launch(void* const* d_in, const int* in_sizes, int n_in,
                              void* d_out, int out_size, void* d_ws, size_t ws_size,
                              hipStream_t stream){
    const float* xyz        = (const float*)d_in[0];
    const float* x          = (const float*)d_in[1];
    const int*   fps        = (const int*)d_in[2];
    const float* pre_bn_g   = (const float*)d_in[4];
    const float* pre_bn_b   = (const float*)d_in[5];
    const float* pre_ffn_g  = (const float*)d_in[7];
    const float* pre_ffn_b  = (const float*)d_in[8];
    const float* pos_bn_g   = (const float*)d_in[10];
    const float* pos_bn_b   = (const float*)d_in[11];
    const float* pos_ffn_g  = (const float*)d_in[13];
    const float* pos_ffn_b  = (const float*)d_in[14];

    float* out_xyz = (float*)d_out;
    float* out_y   = (float*)d_out + (long)B_*S_*3;

    // ws layout (bytes):
    //   0        scsh   (6*256 floats used; reserve 10240)
    //   10240    pb2a (64KB) ; 75776 pb2b (64KB)
    //   141312   Wb (327680) -> 468992
    //   468992   idx (1MB, knn/build) THEN pb (2MB, ext1 convs) -> 2566144
    //   2566144  xT (8MB, until build) THEN A2(2MB)@2566144 + C2(2MB)@4663296
    //   10954752 A1 (64MiB = 67108864) -> 78063616
    //   78063616 Cb (64MiB) -> 145172480
    char* ws = (char*)d_ws;
    float*    scsh  = (float*)(ws + 0);
    float*    pb2a  = (float*)(ws + 10240);
    float*    pb2b  = (float*)(ws + 75776);
    ushort_t* Wb    = (ushort_t*)(ws + 141312);
    int*      idx   = (int*)(ws + 468992);
    float*    pb    = (float*)(ws + 468992);
    float*    xT    = (float*)(ws + 2566144);
    ushort_t* A2    = (ushort_t*)(ws + 2566144);
    ushort_t* C2    = (ushort_t*)(ws + 4663296);
    ushort_t* A1    = (ushort_t*)(ws + 10954752);
    ushort_t* Cb    = (ushort_t*)(ws + 78063616);
    (void)in_sizes; (void)n_in; (void)out_size; (void)ws_size;

    const float inv1 = 1.0f/(float)NCOL1, inv2 = 1.0f/(float)NCOL2;
    const ushort_t* Wp = Wb;            // pre weights (5 mats)
    const ushort_t* Wq = Wb + 5*C_*C_;  // pos weights (5 mats)

    wcvt_kernel<<<640,256,0,stream>>>((const float*)d_in[3], (const float*)d_in[6],
                                      (const float*)d_in[9], (const float*)d_in[12], Wb);
    transpose_kernel<<<B_*(N_/64),256,0,stream>>>(x, xT);
    knn_kernel<<<B_*S_,256,0,stream>>>(xyz, fps, idx, out_xyz);
    build_kernel<<<NCOL1/256,256,0,stream>>>(xT, fps, idx, A1);

    // -------- extraction 1 (ncol = 262144, nb = 2048) --------
    {
        int nb = NCOL1/128;
        const float* G[5]  = {pre_bn_g, pre_bn_g+C_, pre_bn_g+2*C_, pre_bn_g+3*C_, pre_ffn_g};
        const float* Bv[5] = {pre_bn_b, pre_bn_b+C_, pre_bn_b+2*C_, pre_bn_b+3*C_, pre_ffn_b};
        conv_mfma<0,0><<<nb,256,0,stream>>>(A1, nullptr, nullptr, Cb, Wp+0*C_*C_, nullptr, nullptr, nullptr, nullptr, pb, nb, inv1);
        reduce_fin_kernel<<<128,256,0,stream>>>(pb, scsh+0*256, G[0], Bv[0], inv1, nb);
        conv_mfma<1,0><<<nb,256,0,stream>>>(Cb, nullptr, nullptr, Cb, Wp+1*C_*C_, scsh+0*256, nullptr, nullptr, nullptr, pb, nb, inv1);
        reduce_fin_kernel<<<128,256,0,stream>>>(pb, scsh+1*256, G[1], Bv[1], inv1, nb);
        conv_mfma<2,0><<<nb,256,0,stream>>>(Cb, A1, A1, Cb, Wp+2*C_*C_, scsh+1*256, nullptr, nullptr, nullptr, pb, nb, inv1);
        reduce_fin_kernel<<<128,256,0,stream>>>(pb, scsh+2*256, G[2], Bv[2], inv1, nb);
        conv_mfma<1,0><<<nb,256,0,stream>>>(Cb, nullptr, nullptr, Cb, Wp+3*C_*C_, scsh+2*256, nullptr, nullptr, nullptr, pb, nb, inv1);
        reduce_fin_kernel<<<128,256,0,stream>>>(pb, scsh+3*256, G[3], Bv[3], inv1, nb);
        conv_mfma<2,0><<<nb,256,0,stream>>>(Cb, A1, A1, Cb, Wp+4*C_*C_, scsh+3*256, nullptr, nullptr, nullptr, pb, nb, inv1);
        reduce_fin_kernel<<<128,256,0,stream>>>(pb, scsh+4*256, G[4], Bv[4], inv1, nb);
        pool_kernel<<<(NCOL2*64)/256,256,0,stream>>>(Cb, A1, scsh+4*256, A2);
    }

    // -------- extraction 2 (ncol = 8192, nb = 64) --------
    {
        int nb = NCOL2/128;
        const float* G[5]  = {pos_bn_g, pos_bn_g+C_, pos_bn_g+2*C_, pos_bn_g+3*C_, pos_ffn_g};
        const float* Bv[5] = {pos_bn_b, pos_bn_b+C_, pos_bn_b+2*C_, pos_bn_b+3*C_, pos_ffn_b};
        conv_mfma<0,1><<<nb,256,0,stream>>>(A2, nullptr, nullptr, C2, Wq+0*C_*C_, nullptr, nullptr, nullptr, nullptr, pb2a, nb, inv2);
        conv_mfma<1,1><<<nb,256,0,stream>>>(C2, nullptr, nullptr, C2, Wq+1*C_*C_, nullptr, pb2a, G[0], Bv[0], pb2b, nb, inv2);
        conv_mfma<2,1><<<nb,256,0,stream>>>(C2, A2, A2, C2, Wq+2*C_*C_, nullptr, pb2b, G[1], Bv[1], pb2a, nb, inv2);
        conv_mfma<1,1><<<nb,256,0,stream>>>(C2, nullptr, nullptr, C2, Wq+3*C_*C_, nullptr, pb2a, G[2], Bv[2], pb2b, nb, inv2);
        conv_mfma<2,1><<<nb,256,0,stream>>>(C2, A2, A2, C2, Wq+4*C_*C_, nullptr, pb2b, G[3], Bv[3], pb2a, nb, inv2);
        reduce_fin_kernel<<<128,256,0,stream>>>(pb2a, scsh+5*256, G[4], Bv[4], inv2, nb);
        out_kernel<<<(B_*C_*S_)/256,256,0,stream>>>(C2, A2, scsh+5*256, out_y);
    }
}